// Round 1
// baseline (1694.937 us; speedup 1.0000x reference)
//
#include <hip/hip_runtime.h>
#include <hip/hip_bf16.h>

// GCN forward, fp32 end-to-end.
// Pipeline per call: degree hist -> norms -> CSR(dst) build (scan + bucket fill)
// -> embed GEMM (+scaled copy) -> 4x [pull-gather, GEMM(+BN stats), BN finalize,
// BN+ReLU+residual(+scale for next gather)] -> per-graph mean readout.
// Workspace use: ~162 MB.

#define N_NODES 100000
#define N_EDGES 1600000
#define N_GRAPHS 128
#define DIM 128
#define N_LAYERS 4
#define BN_EPS 1e-5f
#define SCAN_NB 98  // ceil(N_NODES / 1024)

// ---------------- degree / norms ----------------
__global__ __launch_bounds__(256) void degree_k(const int* __restrict__ src,
                                                const int* __restrict__ dst,
                                                int* deg_out, int* deg_in) {
  int e = blockIdx.x * 256 + threadIdx.x;
  if (e < N_EDGES) {
    atomicAdd(&deg_out[src[e]], 1);
    atomicAdd(&deg_in[dst[e]], 1);
  }
}

__global__ __launch_bounds__(256) void norm_k(const int* __restrict__ deg_out,
                                              const int* __restrict__ deg_in,
                                              float* __restrict__ norm_src,
                                              float* __restrict__ norm_dst) {
  int i = blockIdx.x * 256 + threadIdx.x;
  if (i < N_NODES) {
    int dso = deg_out[i] > 1 ? deg_out[i] : 1;
    int dsi = deg_in[i] > 1 ? deg_in[i] : 1;
    norm_src[i] = rsqrtf((float)dso);
    norm_dst[i] = rsqrtf((float)dsi);
  }
}

// ---------------- exclusive scan of deg_in -> row_start ----------------
__global__ __launch_bounds__(256) void scan1_k(const int* __restrict__ deg,
                                               int* __restrict__ bsums) {
  __shared__ int sred[256];
  int t = threadIdx.x;
  int i0 = blockIdx.x * 1024 + t * 4;
  int s = 0;
#pragma unroll
  for (int j = 0; j < 4; ++j) {
    int i = i0 + j;
    s += (i < N_NODES) ? deg[i] : 0;
  }
  sred[t] = s;
  __syncthreads();
  for (int off = 128; off > 0; off >>= 1) {
    if (t < off) sred[t] += sred[t + off];
    __syncthreads();
  }
  if (t == 0) bsums[blockIdx.x] = sred[0];
}

__global__ __launch_bounds__(128) void scan2_k(int* __restrict__ bsums,
                                               int* __restrict__ row_start) {
  __shared__ int sd[128];
  int t = threadIdx.x;
  int v = (t < SCAN_NB) ? bsums[t] : 0;
  sd[t] = v;
  __syncthreads();
  for (int off = 1; off < 128; off <<= 1) {
    int tmp = (t >= off) ? sd[t - off] : 0;
    __syncthreads();
    sd[t] += tmp;
    __syncthreads();
  }
  if (t < SCAN_NB) bsums[t] = sd[t] - v;  // exclusive
  if (t == 0) row_start[N_NODES] = N_EDGES;
}

__global__ __launch_bounds__(256) void scan3_k(const int* __restrict__ deg,
                                               const int* __restrict__ bsums,
                                               int* __restrict__ row_start) {
  __shared__ int sd[256];
  int t = threadIdx.x;
  int i0 = blockIdx.x * 1024 + t * 4;
  int d[4];
  int tot = 0;
#pragma unroll
  for (int j = 0; j < 4; ++j) {
    int i = i0 + j;
    d[j] = (i < N_NODES) ? deg[i] : 0;
    tot += d[j];
  }
  sd[t] = tot;
  __syncthreads();
  for (int off = 1; off < 256; off <<= 1) {
    int tmp = (t >= off) ? sd[t - off] : 0;
    __syncthreads();
    sd[t] += tmp;
    __syncthreads();
  }
  int run = bsums[blockIdx.x] + sd[t] - tot;
#pragma unroll
  for (int j = 0; j < 4; ++j) {
    int i = i0 + j;
    if (i < N_NODES) row_start[i] = run;
    run += d[j];
  }
}

__global__ __launch_bounds__(256) void fill_k(const int* __restrict__ src,
                                              const int* __restrict__ dst,
                                              int* __restrict__ cursor,
                                              int* __restrict__ csr_src) {
  int e = blockIdx.x * 256 + threadIdx.x;
  if (e < N_EDGES) {
    int d = dst[e];
    int pos = atomicAdd(&cursor[d], 1);
    csr_src[pos] = src[e];
  }
}

// ---------------- GEMM: Y[N,128] = X[N,128] @ W[128,128] + b ----------------
// 512 threads, per-thread 8 rows x 4 cols register tile, k staged in 32-chunks.
// Optional: scaled_out = Y * norm_src (embed); stats = per-col sum/sumsq (BN).
// In-place safe for X == Y (block writes only its own staged rows, after all
// staging reads complete).
__global__ __launch_bounds__(512) void gemm128(
    const float* X, const float* __restrict__ W, const float* __restrict__ bias,
    float* Y, float* scaled_out, const float* __restrict__ norm_src,
    float* stats) {
  __shared__ float sW[32 * 128];   // [k][c]
  __shared__ float sXt[32 * 132];  // [k][r], padded stride 132
  const int tid = threadIdx.x;
  const int trow = tid & 15;   // 16 row groups x 8 rows
  const int tcol = tid >> 4;   // 32 col groups x 4 cols
  const int r0 = trow * 8;
  const int c0 = tcol * 4;
  const int row_base = blockIdx.x * 128;

  float acc[8][4];
#pragma unroll
  for (int i = 0; i < 8; ++i)
#pragma unroll
    for (int j = 0; j < 4; ++j) acc[i][j] = 0.0f;

  for (int kc = 0; kc < 4; ++kc) {
    {  // stage W chunk [32][128] = 1024 float4
      const float4* Wv = (const float4*)(W + kc * 32 * 128);
      float4* sWv = (float4*)sW;
      sWv[tid] = Wv[tid];
      sWv[tid + 512] = Wv[tid + 512];
    }
#pragma unroll
    for (int it = 0; it < 2; ++it) {  // stage X chunk, transposed
      int idx = it * 512 + tid;  // 0..1023
      int r = idx >> 3;          // 0..127
      int q = idx & 7;           // float4 slot within 32-float k-chunk
      int row = row_base + r;
      float4 v = make_float4(0.f, 0.f, 0.f, 0.f);
      if (row < N_NODES)
        v = *(const float4*)(X + (size_t)row * 128 + kc * 32 + q * 4);
      sXt[(q * 4 + 0) * 132 + r] = v.x;
      sXt[(q * 4 + 1) * 132 + r] = v.y;
      sXt[(q * 4 + 2) * 132 + r] = v.z;
      sXt[(q * 4 + 3) * 132 + r] = v.w;
    }
    __syncthreads();
#pragma unroll
    for (int k = 0; k < 32; ++k) {
      float4 w4 = *(const float4*)(sW + k * 128 + c0);
      float4 a0 = *(const float4*)(sXt + k * 132 + r0);
      float4 a1 = *(const float4*)(sXt + k * 132 + r0 + 4);
      float a[8] = {a0.x, a0.y, a0.z, a0.w, a1.x, a1.y, a1.z, a1.w};
      float w[4] = {w4.x, w4.y, w4.z, w4.w};
#pragma unroll
      for (int i = 0; i < 8; ++i)
#pragma unroll
        for (int j = 0; j < 4; ++j) acc[i][j] += a[i] * w[j];
    }
    __syncthreads();
  }

  float4 b4 = *(const float4*)(bias + c0);
  float ps[4] = {0.f, 0.f, 0.f, 0.f};
  float pq[4] = {0.f, 0.f, 0.f, 0.f};
#pragma unroll
  for (int i = 0; i < 8; ++i) {
    int row = row_base + r0 + i;
    if (row < N_NODES) {
      float4 y;
      y.x = acc[i][0] + b4.x;
      y.y = acc[i][1] + b4.y;
      y.z = acc[i][2] + b4.z;
      y.w = acc[i][3] + b4.w;
      *(float4*)(Y + (size_t)row * 128 + c0) = y;
      if (scaled_out) {
        float ns = norm_src[row];
        *(float4*)(scaled_out + (size_t)row * 128 + c0) =
            make_float4(y.x * ns, y.y * ns, y.z * ns, y.w * ns);
      }
      ps[0] += y.x; ps[1] += y.y; ps[2] += y.z; ps[3] += y.w;
      pq[0] += y.x * y.x; pq[1] += y.y * y.y;
      pq[2] += y.z * y.z; pq[3] += y.w * y.w;
    }
  }
  if (stats) {
    float* red = sXt;              // [16][132]
    float* red2 = sXt + 16 * 132;  // [16][132]
#pragma unroll
    for (int j = 0; j < 4; ++j) {
      red[trow * 132 + c0 + j] = ps[j];
      red2[trow * 132 + c0 + j] = pq[j];
    }
    __syncthreads();
    if (tid < 128) {
      float s = 0.f, q = 0.f;
#pragma unroll
      for (int t = 0; t < 16; ++t) {
        s += red[t * 132 + tid];
        q += red2[t * 132 + tid];
      }
      atomicAdd(&stats[tid], s);
      atomicAdd(&stats[128 + tid], q);
    }
  }
}

// ---------------- BN finalize ----------------
__global__ __launch_bounds__(128) void bn_fin_k(const float* __restrict__ stats,
                                                const float* __restrict__ gamma,
                                                const float* __restrict__ beta,
                                                float* __restrict__ sc_sh) {
  int c = threadIdx.x;
  const float invn = 1.0f / (float)N_NODES;
  float mean = stats[c] * invn;
  float var = stats[128 + c] * invn - mean * mean;
  var = fmaxf(var, 0.f);
  float sc = gamma[c] * rsqrtf(var + BN_EPS);
  sc_sh[c] = sc;
  sc_sh[128 + c] = beta[c] - mean * sc;
}

// ---------------- BN apply + ReLU + residual (+ scale for next gather) -----
__global__ __launch_bounds__(256) void bnrelu_k(
    const float4* __restrict__ hl, float4* __restrict__ A,
    float4* __restrict__ S, const float* __restrict__ sc_sh,
    const float* __restrict__ norm_src, int write_scaled) {
  int idx = blockIdx.x * 256 + threadIdx.x;  // < N_NODES*32
  int node = idx >> 5;
  int c4 = idx & 31;
  const float4* sv = (const float4*)sc_sh;
  float4 s = sv[c4], b = sv[32 + c4];
  float4 hv = hl[idx], av = A[idx];
  float4 v;
  v.x = fmaxf(hv.x * s.x + b.x, 0.f) + av.x;
  v.y = fmaxf(hv.y * s.y + b.y, 0.f) + av.y;
  v.z = fmaxf(hv.z * s.z + b.z, 0.f) + av.z;
  v.w = fmaxf(hv.w * s.w + b.w, 0.f) + av.w;
  A[idx] = v;
  if (write_scaled) {
    float n = norm_src[node];
    S[idx] = make_float4(v.x * n, v.y * n, v.z * n, v.w * n);
  }
}

// ---------------- pull aggregation: agg[i] = norm_dst[i]*sum_{e:dst=i} Hs[src]
// half-wave (32 lanes) per node; lane owns one float4 (4 cols) of the row.
__global__ __launch_bounds__(256) void gather_k(
    const float4* __restrict__ Hs, const int* __restrict__ row_start,
    const int* __restrict__ csr_src, const float* __restrict__ norm_dst,
    float4* __restrict__ out) {
  int hw = (blockIdx.x * 256 + threadIdx.x) >> 5;
  int lane = threadIdx.x & 31;
  if (hw >= N_NODES) return;
  int s0 = row_start[hw], s1 = row_start[hw + 1];
  float4 acc = make_float4(0.f, 0.f, 0.f, 0.f);
  for (int e = s0; e < s1; e += 32) {
    int nrem = s1 - e;
    int cnt = nrem < 32 ? nrem : 32;
    int idx = (lane < cnt) ? csr_src[e + lane] : 0;
    int j = 0;
    for (; j + 4 <= cnt; j += 4) {
      int sa = __shfl(idx, j, 32);
      int sb = __shfl(idx, j + 1, 32);
      int sc = __shfl(idx, j + 2, 32);
      int sd = __shfl(idx, j + 3, 32);
      float4 va = Hs[(size_t)sa * 32 + lane];
      float4 vb = Hs[(size_t)sb * 32 + lane];
      float4 vc = Hs[(size_t)sc * 32 + lane];
      float4 vd = Hs[(size_t)sd * 32 + lane];
      acc.x += va.x + vb.x + vc.x + vd.x;
      acc.y += va.y + vb.y + vc.y + vd.y;
      acc.z += va.z + vb.z + vc.z + vd.z;
      acc.w += va.w + vb.w + vc.w + vd.w;
    }
    for (; j < cnt; ++j) {
      int sj = __shfl(idx, j, 32);
      float4 v = Hs[(size_t)sj * 32 + lane];
      acc.x += v.x; acc.y += v.y; acc.z += v.z; acc.w += v.w;
    }
  }
  float nd = norm_dst[hw];
  out[(size_t)hw * 32 + lane] =
      make_float4(acc.x * nd, acc.y * nd, acc.z * nd, acc.w * nd);
}

// ---------------- readout ----------------
__global__ __launch_bounds__(256) void gcnt_k(const int* __restrict__ gid,
                                              int* gcnt) {
  int i = blockIdx.x * 256 + threadIdx.x;
  if (i < N_NODES) atomicAdd(&gcnt[gid[i]], 1);
}

__global__ __launch_bounds__(128) void gsum_k(const float* __restrict__ A,
                                              const int* __restrict__ gid,
                                              float* gsum) {
  int c = threadIdx.x;
  int n0 = blockIdx.x * 512;
  int n1 = n0 + 512;
  if (n1 > N_NODES) n1 = N_NODES;
  int cur = gid[n0];
  float local = 0.f;
  for (int n = n0; n < n1; ++n) {
    int g = gid[n];  // sorted: uniform per block warp, few changes
    if (g != cur) {
      atomicAdd(&gsum[cur * 128 + c], local);
      local = 0.f;
      cur = g;
    }
    local += A[(size_t)n * 128 + c];
  }
  atomicAdd(&gsum[cur * 128 + c], local);
}

__global__ __launch_bounds__(128) void gout_k(const float* __restrict__ gsum,
                                              const int* __restrict__ gcnt,
                                              float* __restrict__ out) {
  int g = blockIdx.x, c = threadIdx.x;
  float cnt = (float)gcnt[g];
  if (cnt < 1.f) cnt = 1.f;
  out[g * 128 + c] = gsum[g * 128 + c] / cnt;
}

// ---------------- launch ----------------
extern "C" void kernel_launch(void* const* d_in, const int* in_sizes, int n_in,
                              void* d_out, int out_size, void* d_ws,
                              size_t ws_size, hipStream_t stream) {
  const float* h = (const float*)d_in[0];
  const int* src = (const int*)d_in[1];
  const int* dst = (const int*)d_in[2];
  const int* gid = (const int*)d_in[3];
  const float* W_embed = (const float*)d_in[4];
  const float* b_embed = (const float*)d_in[5];
  const float* W_layers = (const float*)d_in[6];
  const float* b_layers = (const float*)d_in[7];
  const float* gamma = (const float*)d_in[8];
  const float* beta = (const float*)d_in[9];
  float* out = (float*)d_out;
  (void)in_sizes; (void)n_in; (void)out_size; (void)ws_size;

  char* ws = (char*)d_ws;
  size_t o = 0;
  auto alloc = [&](size_t bytes) -> char* {
    char* p = ws + o;
    o = (o + bytes + 255) & ~(size_t)255;
    return p;
  };
  float* norm_src = (float*)alloc(N_NODES * 4);
  float* norm_dst = (float*)alloc(N_NODES * 4);
  int* deg_out = (int*)alloc(N_NODES * 4);  // reused as fill cursor
  int* deg_in = (int*)alloc(N_NODES * 4);   // adjacent to deg_out (one memset)
  int* row_start = (int*)alloc((N_NODES + 1) * 4);
  int* bsums = (int*)alloc(SCAN_NB * 4);
  int* csr_src = (int*)alloc((size_t)N_EDGES * 4);
  float* stats4 = (float*)alloc(N_LAYERS * 256 * 4);  // per-layer sum|sumsq
  float* gsum = (float*)alloc(N_GRAPHS * 128 * 4);    // adjacent to stats4
  int* gcnt = (int*)alloc(N_GRAPHS * 4);              // adjacent to gsum
  float* sc_sh = (float*)alloc(256 * 4);
  float* A = (float*)alloc((size_t)N_NODES * 128 * 4);   // residual h
  float* P0 = (float*)alloc((size_t)N_NODES * 128 * 4);  // h * norm_src
  float* P1 = (float*)alloc((size_t)N_NODES * 128 * 4);  // agg / hl (in-place)

  // zero accumulators (deg_out+deg_in contiguous; stats4+gsum+gcnt contiguous)
  hipMemsetAsync(deg_out, 0, 2 * 400128, stream);
  hipMemsetAsync(stats4, 0, 4096 + 65536 + 512, stream);

  degree_k<<<(N_EDGES + 255) / 256, 256, 0, stream>>>(src, dst, deg_out, deg_in);
  norm_k<<<(N_NODES + 255) / 256, 256, 0, stream>>>(deg_out, deg_in, norm_src,
                                                    norm_dst);
  scan1_k<<<SCAN_NB, 256, 0, stream>>>(deg_in, bsums);
  scan2_k<<<1, 128, 0, stream>>>(bsums, row_start);
  scan3_k<<<SCAN_NB, 256, 0, stream>>>(deg_in, bsums, row_start);
  hipMemcpyAsync(deg_out, row_start, N_NODES * 4, hipMemcpyDeviceToDevice,
                 stream);  // cursor = row_start copy
  fill_k<<<(N_EDGES + 255) / 256, 256, 0, stream>>>(src, dst, deg_out, csr_src);

  // embed: A = h @ W_embed + b ; P0 = A * norm_src
  gemm128<<<(N_NODES + 127) / 128, 512, 0, stream>>>(h, W_embed, b_embed, A, P0,
                                                     norm_src, nullptr);

  for (int l = 0; l < N_LAYERS; ++l) {
    gather_k<<<(N_NODES * 32 + 255) / 256, 256, 0, stream>>>(
        (const float4*)P0, row_start, csr_src, norm_dst, (float4*)P1);
    gemm128<<<(N_NODES + 127) / 128, 512, 0, stream>>>(
        P1, W_layers + (size_t)l * DIM * DIM, b_layers + l * DIM, P1, nullptr,
        nullptr, stats4 + l * 256);
    bn_fin_k<<<1, 128, 0, stream>>>(stats4 + l * 256, gamma + l * DIM,
                                    beta + l * DIM, sc_sh);
    bnrelu_k<<<(N_NODES * 32 + 255) / 256, 256, 0, stream>>>(
        (const float4*)P1, (float4*)A, (float4*)P0, sc_sh, norm_src,
        (l < N_LAYERS - 1) ? 1 : 0);
  }

  gcnt_k<<<(N_NODES + 255) / 256, 256, 0, stream>>>(gid, gcnt);
  gsum_k<<<(N_NODES + 511) / 512, 128, 0, stream>>>(A, gid, gsum);
  gout_k<<<N_GRAPHS, 128, 0, stream>>>(gsum, gcnt, out);
}

// Round 2
// 1313.034 us; speedup vs baseline: 1.2909x; 1.2909x over previous
//
#include <hip/hip_runtime.h>
#include <hip/hip_bf16.h>

// GCN forward, fp32 end-to-end.
// Pipeline per call: degree hist -> norms -> CSR(dst) build (scan + bucket fill)
// -> embed GEMM (+scaled copy) -> 4x [pull-gather, GEMM(+BN stats), BN finalize,
// BN+ReLU+residual(+scale for next gather)] -> per-graph mean readout.
// R1: gcnt via binary search on sorted graph_id (was 285us atomic-contended
// histogram); gsum_k 128 rows/block (was 512, serial load chain).

#define N_NODES 100000
#define N_EDGES 1600000
#define N_GRAPHS 128
#define DIM 128
#define N_LAYERS 4
#define BN_EPS 1e-5f
#define SCAN_NB 98  // ceil(N_NODES / 1024)

// ---------------- degree / norms ----------------
__global__ __launch_bounds__(256) void degree_k(const int* __restrict__ src,
                                                const int* __restrict__ dst,
                                                int* deg_out, int* deg_in) {
  int e = blockIdx.x * 256 + threadIdx.x;
  if (e < N_EDGES) {
    atomicAdd(&deg_out[src[e]], 1);
    atomicAdd(&deg_in[dst[e]], 1);
  }
}

__global__ __launch_bounds__(256) void norm_k(const int* __restrict__ deg_out,
                                              const int* __restrict__ deg_in,
                                              float* __restrict__ norm_src,
                                              float* __restrict__ norm_dst) {
  int i = blockIdx.x * 256 + threadIdx.x;
  if (i < N_NODES) {
    int dso = deg_out[i] > 1 ? deg_out[i] : 1;
    int dsi = deg_in[i] > 1 ? deg_in[i] : 1;
    norm_src[i] = rsqrtf((float)dso);
    norm_dst[i] = rsqrtf((float)dsi);
  }
}

// ---------------- exclusive scan of deg_in -> row_start ----------------
__global__ __launch_bounds__(256) void scan1_k(const int* __restrict__ deg,
                                               int* __restrict__ bsums) {
  __shared__ int sred[256];
  int t = threadIdx.x;
  int i0 = blockIdx.x * 1024 + t * 4;
  int s = 0;
#pragma unroll
  for (int j = 0; j < 4; ++j) {
    int i = i0 + j;
    s += (i < N_NODES) ? deg[i] : 0;
  }
  sred[t] = s;
  __syncthreads();
  for (int off = 128; off > 0; off >>= 1) {
    if (t < off) sred[t] += sred[t + off];
    __syncthreads();
  }
  if (t == 0) bsums[blockIdx.x] = sred[0];
}

__global__ __launch_bounds__(128) void scan2_k(int* __restrict__ bsums,
                                               int* __restrict__ row_start) {
  __shared__ int sd[128];
  int t = threadIdx.x;
  int v = (t < SCAN_NB) ? bsums[t] : 0;
  sd[t] = v;
  __syncthreads();
  for (int off = 1; off < 128; off <<= 1) {
    int tmp = (t >= off) ? sd[t - off] : 0;
    __syncthreads();
    sd[t] += tmp;
    __syncthreads();
  }
  if (t < SCAN_NB) bsums[t] = sd[t] - v;  // exclusive
  if (t == 0) row_start[N_NODES] = N_EDGES;
}

__global__ __launch_bounds__(256) void scan3_k(const int* __restrict__ deg,
                                               const int* __restrict__ bsums,
                                               int* __restrict__ row_start) {
  __shared__ int sd[256];
  int t = threadIdx.x;
  int i0 = blockIdx.x * 1024 + t * 4;
  int d[4];
  int tot = 0;
#pragma unroll
  for (int j = 0; j < 4; ++j) {
    int i = i0 + j;
    d[j] = (i < N_NODES) ? deg[i] : 0;
    tot += d[j];
  }
  sd[t] = tot;
  __syncthreads();
  for (int off = 1; off < 256; off <<= 1) {
    int tmp = (t >= off) ? sd[t - off] : 0;
    __syncthreads();
    sd[t] += tmp;
    __syncthreads();
  }
  int run = bsums[blockIdx.x] + sd[t] - tot;
#pragma unroll
  for (int j = 0; j < 4; ++j) {
    int i = i0 + j;
    if (i < N_NODES) row_start[i] = run;
    run += d[j];
  }
}

__global__ __launch_bounds__(256) void fill_k(const int* __restrict__ src,
                                              const int* __restrict__ dst,
                                              int* __restrict__ cursor,
                                              int* __restrict__ csr_src) {
  int e = blockIdx.x * 256 + threadIdx.x;
  if (e < N_EDGES) {
    int d = dst[e];
    int pos = atomicAdd(&cursor[d], 1);
    csr_src[pos] = src[e];
  }
}

// ---------------- GEMM: Y[N,128] = X[N,128] @ W[128,128] + b ----------------
// 512 threads, per-thread 8 rows x 4 cols register tile, k staged in 32-chunks.
// Optional: scaled_out = Y * norm_src (embed); stats = per-col sum/sumsq (BN).
// In-place safe for X == Y.
__global__ __launch_bounds__(512) void gemm128(
    const float* X, const float* __restrict__ W, const float* __restrict__ bias,
    float* Y, float* scaled_out, const float* __restrict__ norm_src,
    float* stats) {
  __shared__ float sW[32 * 128];   // [k][c]
  __shared__ float sXt[32 * 132];  // [k][r], padded stride 132
  const int tid = threadIdx.x;
  const int trow = tid & 15;   // 16 row groups x 8 rows
  const int tcol = tid >> 4;   // 32 col groups x 4 cols
  const int r0 = trow * 8;
  const int c0 = tcol * 4;
  const int row_base = blockIdx.x * 128;

  float acc[8][4];
#pragma unroll
  for (int i = 0; i < 8; ++i)
#pragma unroll
    for (int j = 0; j < 4; ++j) acc[i][j] = 0.0f;

  for (int kc = 0; kc < 4; ++kc) {
    {  // stage W chunk [32][128] = 1024 float4
      const float4* Wv = (const float4*)(W + kc * 32 * 128);
      float4* sWv = (float4*)sW;
      sWv[tid] = Wv[tid];
      sWv[tid + 512] = Wv[tid + 512];
    }
#pragma unroll
    for (int it = 0; it < 2; ++it) {  // stage X chunk, transposed
      int idx = it * 512 + tid;  // 0..1023
      int r = idx >> 3;          // 0..127
      int q = idx & 7;           // float4 slot within 32-float k-chunk
      int row = row_base + r;
      float4 v = make_float4(0.f, 0.f, 0.f, 0.f);
      if (row < N_NODES)
        v = *(const float4*)(X + (size_t)row * 128 + kc * 32 + q * 4);
      sXt[(q * 4 + 0) * 132 + r] = v.x;
      sXt[(q * 4 + 1) * 132 + r] = v.y;
      sXt[(q * 4 + 2) * 132 + r] = v.z;
      sXt[(q * 4 + 3) * 132 + r] = v.w;
    }
    __syncthreads();
#pragma unroll
    for (int k = 0; k < 32; ++k) {
      float4 w4 = *(const float4*)(sW + k * 128 + c0);
      float4 a0 = *(const float4*)(sXt + k * 132 + r0);
      float4 a1 = *(const float4*)(sXt + k * 132 + r0 + 4);
      float a[8] = {a0.x, a0.y, a0.z, a0.w, a1.x, a1.y, a1.z, a1.w};
      float w[4] = {w4.x, w4.y, w4.z, w4.w};
#pragma unroll
      for (int i = 0; i < 8; ++i)
#pragma unroll
        for (int j = 0; j < 4; ++j) acc[i][j] += a[i] * w[j];
    }
    __syncthreads();
  }

  float4 b4 = *(const float4*)(bias + c0);
  float ps[4] = {0.f, 0.f, 0.f, 0.f};
  float pq[4] = {0.f, 0.f, 0.f, 0.f};
#pragma unroll
  for (int i = 0; i < 8; ++i) {
    int row = row_base + r0 + i;
    if (row < N_NODES) {
      float4 y;
      y.x = acc[i][0] + b4.x;
      y.y = acc[i][1] + b4.y;
      y.z = acc[i][2] + b4.z;
      y.w = acc[i][3] + b4.w;
      *(float4*)(Y + (size_t)row * 128 + c0) = y;
      if (scaled_out) {
        float ns = norm_src[row];
        *(float4*)(scaled_out + (size_t)row * 128 + c0) =
            make_float4(y.x * ns, y.y * ns, y.z * ns, y.w * ns);
      }
      ps[0] += y.x; ps[1] += y.y; ps[2] += y.z; ps[3] += y.w;
      pq[0] += y.x * y.x; pq[1] += y.y * y.y;
      pq[2] += y.z * y.z; pq[3] += y.w * y.w;
    }
  }
  if (stats) {
    float* red = sXt;              // [16][132]
    float* red2 = sXt + 16 * 132;  // [16][132]
#pragma unroll
    for (int j = 0; j < 4; ++j) {
      red[trow * 132 + c0 + j] = ps[j];
      red2[trow * 132 + c0 + j] = pq[j];
    }
    __syncthreads();
    if (tid < 128) {
      float s = 0.f, q = 0.f;
#pragma unroll
      for (int t = 0; t < 16; ++t) {
        s += red[t * 132 + tid];
        q += red2[t * 132 + tid];
      }
      atomicAdd(&stats[tid], s);
      atomicAdd(&stats[128 + tid], q);
    }
  }
}

// ---------------- BN finalize ----------------
__global__ __launch_bounds__(128) void bn_fin_k(const float* __restrict__ stats,
                                                const float* __restrict__ gamma,
                                                const float* __restrict__ beta,
                                                float* __restrict__ sc_sh) {
  int c = threadIdx.x;
  const float invn = 1.0f / (float)N_NODES;
  float mean = stats[c] * invn;
  float var = stats[128 + c] * invn - mean * mean;
  var = fmaxf(var, 0.f);
  float sc = gamma[c] * rsqrtf(var + BN_EPS);
  sc_sh[c] = sc;
  sc_sh[128 + c] = beta[c] - mean * sc;
}

// ---------------- BN apply + ReLU + residual (+ scale for next gather) -----
__global__ __launch_bounds__(256) void bnrelu_k(
    const float4* __restrict__ hl, float4* __restrict__ A,
    float4* __restrict__ S, const float* __restrict__ sc_sh,
    const float* __restrict__ norm_src, int write_scaled) {
  int idx = blockIdx.x * 256 + threadIdx.x;  // < N_NODES*32
  int node = idx >> 5;
  int c4 = idx & 31;
  const float4* sv = (const float4*)sc_sh;
  float4 s = sv[c4], b = sv[32 + c4];
  float4 hv = hl[idx], av = A[idx];
  float4 v;
  v.x = fmaxf(hv.x * s.x + b.x, 0.f) + av.x;
  v.y = fmaxf(hv.y * s.y + b.y, 0.f) + av.y;
  v.z = fmaxf(hv.z * s.z + b.z, 0.f) + av.z;
  v.w = fmaxf(hv.w * s.w + b.w, 0.f) + av.w;
  A[idx] = v;
  if (write_scaled) {
    float n = norm_src[node];
    S[idx] = make_float4(v.x * n, v.y * n, v.z * n, v.w * n);
  }
}

// ---------------- pull aggregation: agg[i] = norm_dst[i]*sum_{e:dst=i} Hs[src]
// half-wave (32 lanes) per node; lane owns one float4 (4 cols) of the row.
__global__ __launch_bounds__(256) void gather_k(
    const float4* __restrict__ Hs, const int* __restrict__ row_start,
    const int* __restrict__ csr_src, const float* __restrict__ norm_dst,
    float4* __restrict__ out) {
  int hw = (blockIdx.x * 256 + threadIdx.x) >> 5;
  int lane = threadIdx.x & 31;
  if (hw >= N_NODES) return;
  int s0 = row_start[hw], s1 = row_start[hw + 1];
  float4 acc = make_float4(0.f, 0.f, 0.f, 0.f);
  for (int e = s0; e < s1; e += 32) {
    int nrem = s1 - e;
    int cnt = nrem < 32 ? nrem : 32;
    int idx = (lane < cnt) ? csr_src[e + lane] : 0;
    int j = 0;
    for (; j + 4 <= cnt; j += 4) {
      int sa = __shfl(idx, j, 32);
      int sb = __shfl(idx, j + 1, 32);
      int sc = __shfl(idx, j + 2, 32);
      int sd = __shfl(idx, j + 3, 32);
      float4 va = Hs[(size_t)sa * 32 + lane];
      float4 vb = Hs[(size_t)sb * 32 + lane];
      float4 vc = Hs[(size_t)sc * 32 + lane];
      float4 vd = Hs[(size_t)sd * 32 + lane];
      acc.x += va.x + vb.x + vc.x + vd.x;
      acc.y += va.y + vb.y + vc.y + vd.y;
      acc.z += va.z + vb.z + vc.z + vd.z;
      acc.w += va.w + vb.w + vc.w + vd.w;
    }
    for (; j < cnt; ++j) {
      int sj = __shfl(idx, j, 32);
      float4 v = Hs[(size_t)sj * 32 + lane];
      acc.x += v.x; acc.y += v.y; acc.z += v.z; acc.w += v.w;
    }
  }
  float nd = norm_dst[hw];
  out[(size_t)hw * 32 + lane] =
      make_float4(acc.x * nd, acc.y * nd, acc.z * nd, acc.w * nd);
}

// ---------------- readout ----------------
// graph_id is sorted -> per-graph segment boundaries via binary search.
// gstart[g] = first index with gid[i] >= g; gstart[128] = N_NODES.
__global__ __launch_bounds__(256) void gbounds_k(const int* __restrict__ gid,
                                                 int* __restrict__ gstart) {
  int g = threadIdx.x;  // 0..128
  if (g > N_GRAPHS) return;
  int lo = 0, hi = N_NODES;
  while (lo < hi) {
    int mid = (lo + hi) >> 1;
    if (gid[mid] < g) lo = mid + 1; else hi = mid;
  }
  gstart[g] = lo;
}

__global__ __launch_bounds__(128) void gsum_k(const float* __restrict__ A,
                                              const int* __restrict__ gid,
                                              float* gsum) {
  int c = threadIdx.x;
  int n0 = blockIdx.x * 128;
  int n1 = n0 + 128;
  if (n1 > N_NODES) n1 = N_NODES;
  int cur = gid[n0];
  float local = 0.f;
  for (int n = n0; n < n1; ++n) {
    int g = gid[n];  // sorted: few changes per block
    if (g != cur) {
      atomicAdd(&gsum[cur * 128 + c], local);
      local = 0.f;
      cur = g;
    }
    local += A[(size_t)n * 128 + c];
  }
  atomicAdd(&gsum[cur * 128 + c], local);
}

__global__ __launch_bounds__(128) void gout_k(const float* __restrict__ gsum,
                                              const int* __restrict__ gstart,
                                              float* __restrict__ out) {
  int g = blockIdx.x, c = threadIdx.x;
  float cnt = (float)(gstart[g + 1] - gstart[g]);
  if (cnt < 1.f) cnt = 1.f;
  out[g * 128 + c] = gsum[g * 128 + c] / cnt;
}

// ---------------- launch ----------------
extern "C" void kernel_launch(void* const* d_in, const int* in_sizes, int n_in,
                              void* d_out, int out_size, void* d_ws,
                              size_t ws_size, hipStream_t stream) {
  const float* h = (const float*)d_in[0];
  const int* src = (const int*)d_in[1];
  const int* dst = (const int*)d_in[2];
  const int* gid = (const int*)d_in[3];
  const float* W_embed = (const float*)d_in[4];
  const float* b_embed = (const float*)d_in[5];
  const float* W_layers = (const float*)d_in[6];
  const float* b_layers = (const float*)d_in[7];
  const float* gamma = (const float*)d_in[8];
  const float* beta = (const float*)d_in[9];
  float* out = (float*)d_out;
  (void)in_sizes; (void)n_in; (void)out_size; (void)ws_size;

  char* ws = (char*)d_ws;
  size_t o = 0;
  auto alloc = [&](size_t bytes) -> char* {
    char* p = ws + o;
    o = (o + bytes + 255) & ~(size_t)255;
    return p;
  };
  float* norm_src = (float*)alloc(N_NODES * 4);
  float* norm_dst = (float*)alloc(N_NODES * 4);
  int* deg_out = (int*)alloc(N_NODES * 4);  // reused as fill cursor
  int* deg_in = (int*)alloc(N_NODES * 4);   // adjacent to deg_out (one memset)
  int* row_start = (int*)alloc((N_NODES + 1) * 4);
  int* bsums = (int*)alloc(SCAN_NB * 4);
  int* csr_src = (int*)alloc((size_t)N_EDGES * 4);
  float* stats4 = (float*)alloc(N_LAYERS * 256 * 4);  // per-layer sum|sumsq
  float* gsum = (float*)alloc(N_GRAPHS * 128 * 4);    // adjacent to stats4
  int* gstart = (int*)alloc((N_GRAPHS + 1) * 4);
  float* sc_sh = (float*)alloc(256 * 4);
  float* A = (float*)alloc((size_t)N_NODES * 128 * 4);   // residual h
  float* P0 = (float*)alloc((size_t)N_NODES * 128 * 4);  // h * norm_src
  float* P1 = (float*)alloc((size_t)N_NODES * 128 * 4);  // agg / hl (in-place)

  // zero accumulators (deg_out+deg_in contiguous; stats4+gsum contiguous)
  hipMemsetAsync(deg_out, 0, 2 * 400128, stream);
  hipMemsetAsync(stats4, 0, 4096 + 65536, stream);

  degree_k<<<(N_EDGES + 255) / 256, 256, 0, stream>>>(src, dst, deg_out, deg_in);
  norm_k<<<(N_NODES + 255) / 256, 256, 0, stream>>>(deg_out, deg_in, norm_src,
                                                    norm_dst);
  scan1_k<<<SCAN_NB, 256, 0, stream>>>(deg_in, bsums);
  scan2_k<<<1, 128, 0, stream>>>(bsums, row_start);
  scan3_k<<<SCAN_NB, 256, 0, stream>>>(deg_in, bsums, row_start);
  hipMemcpyAsync(deg_out, row_start, N_NODES * 4, hipMemcpyDeviceToDevice,
                 stream);  // cursor = row_start copy
  fill_k<<<(N_EDGES + 255) / 256, 256, 0, stream>>>(src, dst, deg_out, csr_src);

  // embed: A = h @ W_embed + b ; P0 = A * norm_src
  gemm128<<<(N_NODES + 127) / 128, 512, 0, stream>>>(h, W_embed, b_embed, A, P0,
                                                     norm_src, nullptr);

  for (int l = 0; l < N_LAYERS; ++l) {
    gather_k<<<(N_NODES * 32 + 255) / 256, 256, 0, stream>>>(
        (const float4*)P0, row_start, csr_src, norm_dst, (float4*)P1);
    gemm128<<<(N_NODES + 127) / 128, 512, 0, stream>>>(
        P1, W_layers + (size_t)l * DIM * DIM, b_layers + l * DIM, P1, nullptr,
        nullptr, stats4 + l * 256);
    bn_fin_k<<<1, 128, 0, stream>>>(stats4 + l * 256, gamma + l * DIM,
                                    beta + l * DIM, sc_sh);
    bnrelu_k<<<(N_NODES * 32 + 255) / 256, 256, 0, stream>>>(
        (const float4*)P1, (float4*)A, (float4*)P0, sc_sh, norm_src,
        (l < N_LAYERS - 1) ? 1 : 0);
  }

  gbounds_k<<<1, 256, 0, stream>>>(gid, gstart);
  gsum_k<<<(N_NODES + 127) / 128, 128, 0, stream>>>(A, gid, gsum);
  gout_k<<<N_GRAPHS, 128, 0, stream>>>(gsum, gstart, out);
}

// Round 3
// 1087.974 us; speedup vs baseline: 1.5579x; 1.2069x over previous
//
#include <hip/hip_runtime.h>
#include <hip/hip_bf16.h>
#include <hip/hip_fp16.h>

// GCN forward. fp32 everywhere except the gather operand (h*norm_src), which
// is stored fp16 to halve the 819MB/layer gather read traffic. Accumulation
// and GEMM stay fp32.
// R1: gcnt via binary search (was 285us atomic histogram).
// R2: fp16 gather operand; 16 lanes/node gather (16B/lane loads).

#define N_NODES 100000
#define N_EDGES 1600000
#define N_GRAPHS 128
#define DIM 128
#define N_LAYERS 4
#define BN_EPS 1e-5f
#define SCAN_NB 98  // ceil(N_NODES / 1024)

// ---------------- degree / norms ----------------
__global__ __launch_bounds__(256) void degree_k(const int* __restrict__ src,
                                                const int* __restrict__ dst,
                                                int* deg_out, int* deg_in) {
  int e = blockIdx.x * 256 + threadIdx.x;
  if (e < N_EDGES) {
    atomicAdd(&deg_out[src[e]], 1);
    atomicAdd(&deg_in[dst[e]], 1);
  }
}

__global__ __launch_bounds__(256) void norm_k(const int* __restrict__ deg_out,
                                              const int* __restrict__ deg_in,
                                              float* __restrict__ norm_src,
                                              float* __restrict__ norm_dst) {
  int i = blockIdx.x * 256 + threadIdx.x;
  if (i < N_NODES) {
    int dso = deg_out[i] > 1 ? deg_out[i] : 1;
    int dsi = deg_in[i] > 1 ? deg_in[i] : 1;
    norm_src[i] = rsqrtf((float)dso);
    norm_dst[i] = rsqrtf((float)dsi);
  }
}

// ---------------- exclusive scan of deg_in -> row_start ----------------
__global__ __launch_bounds__(256) void scan1_k(const int* __restrict__ deg,
                                               int* __restrict__ bsums) {
  __shared__ int sred[256];
  int t = threadIdx.x;
  int i0 = blockIdx.x * 1024 + t * 4;
  int s = 0;
#pragma unroll
  for (int j = 0; j < 4; ++j) {
    int i = i0 + j;
    s += (i < N_NODES) ? deg[i] : 0;
  }
  sred[t] = s;
  __syncthreads();
  for (int off = 128; off > 0; off >>= 1) {
    if (t < off) sred[t] += sred[t + off];
    __syncthreads();
  }
  if (t == 0) bsums[blockIdx.x] = sred[0];
}

__global__ __launch_bounds__(128) void scan2_k(int* __restrict__ bsums,
                                               int* __restrict__ row_start) {
  __shared__ int sd[128];
  int t = threadIdx.x;
  int v = (t < SCAN_NB) ? bsums[t] : 0;
  sd[t] = v;
  __syncthreads();
  for (int off = 1; off < 128; off <<= 1) {
    int tmp = (t >= off) ? sd[t - off] : 0;
    __syncthreads();
    sd[t] += tmp;
    __syncthreads();
  }
  if (t < SCAN_NB) bsums[t] = sd[t] - v;  // exclusive
  if (t == 0) row_start[N_NODES] = N_EDGES;
}

__global__ __launch_bounds__(256) void scan3_k(const int* __restrict__ deg,
                                               const int* __restrict__ bsums,
                                               int* __restrict__ row_start) {
  __shared__ int sd[256];
  int t = threadIdx.x;
  int i0 = blockIdx.x * 1024 + t * 4;
  int d[4];
  int tot = 0;
#pragma unroll
  for (int j = 0; j < 4; ++j) {
    int i = i0 + j;
    d[j] = (i < N_NODES) ? deg[i] : 0;
    tot += d[j];
  }
  sd[t] = tot;
  __syncthreads();
  for (int off = 1; off < 256; off <<= 1) {
    int tmp = (t >= off) ? sd[t - off] : 0;
    __syncthreads();
    sd[t] += tmp;
    __syncthreads();
  }
  int run = bsums[blockIdx.x] + sd[t] - tot;
#pragma unroll
  for (int j = 0; j < 4; ++j) {
    int i = i0 + j;
    if (i < N_NODES) row_start[i] = run;
    run += d[j];
  }
}

__global__ __launch_bounds__(256) void fill_k(const int* __restrict__ src,
                                              const int* __restrict__ dst,
                                              int* __restrict__ cursor,
                                              int* __restrict__ csr_src) {
  int e = blockIdx.x * 256 + threadIdx.x;
  if (e < N_EDGES) {
    int d = dst[e];
    int pos = atomicAdd(&cursor[d], 1);
    csr_src[pos] = src[e];
  }
}

// ---------------- GEMM: Y[N,128] = X[N,128] @ W[128,128] + b ----------------
// 512 threads, per-thread 8 rows x 4 cols register tile, k staged in 32-chunks.
// Optional: scaled_out (fp16) = Y * norm_src; stats = per-col sum/sumsq (BN).
// In-place safe for X == Y.
__global__ __launch_bounds__(512) void gemm128(
    const float* X, const float* __restrict__ W, const float* __restrict__ bias,
    float* Y, __half* scaled_out, const float* __restrict__ norm_src,
    float* stats) {
  __shared__ float sW[32 * 128];   // [k][c]
  __shared__ float sXt[32 * 132];  // [k][r], padded stride 132
  const int tid = threadIdx.x;
  const int trow = tid & 15;   // 16 row groups x 8 rows
  const int tcol = tid >> 4;   // 32 col groups x 4 cols
  const int r0 = trow * 8;
  const int c0 = tcol * 4;
  const int row_base = blockIdx.x * 128;

  float acc[8][4];
#pragma unroll
  for (int i = 0; i < 8; ++i)
#pragma unroll
    for (int j = 0; j < 4; ++j) acc[i][j] = 0.0f;

  for (int kc = 0; kc < 4; ++kc) {
    {  // stage W chunk [32][128] = 1024 float4
      const float4* Wv = (const float4*)(W + kc * 32 * 128);
      float4* sWv = (float4*)sW;
      sWv[tid] = Wv[tid];
      sWv[tid + 512] = Wv[tid + 512];
    }
#pragma unroll
    for (int it = 0; it < 2; ++it) {  // stage X chunk, transposed
      int idx = it * 512 + tid;  // 0..1023
      int r = idx >> 3;          // 0..127
      int q = idx & 7;           // float4 slot within 32-float k-chunk
      int row = row_base + r;
      float4 v = make_float4(0.f, 0.f, 0.f, 0.f);
      if (row < N_NODES)
        v = *(const float4*)(X + (size_t)row * 128 + kc * 32 + q * 4);
      sXt[(q * 4 + 0) * 132 + r] = v.x;
      sXt[(q * 4 + 1) * 132 + r] = v.y;
      sXt[(q * 4 + 2) * 132 + r] = v.z;
      sXt[(q * 4 + 3) * 132 + r] = v.w;
    }
    __syncthreads();
#pragma unroll
    for (int k = 0; k < 32; ++k) {
      float4 w4 = *(const float4*)(sW + k * 128 + c0);
      float4 a0 = *(const float4*)(sXt + k * 132 + r0);
      float4 a1 = *(const float4*)(sXt + k * 132 + r0 + 4);
      float a[8] = {a0.x, a0.y, a0.z, a0.w, a1.x, a1.y, a1.z, a1.w};
      float w[4] = {w4.x, w4.y, w4.z, w4.w};
#pragma unroll
      for (int i = 0; i < 8; ++i)
#pragma unroll
        for (int j = 0; j < 4; ++j) acc[i][j] += a[i] * w[j];
    }
    __syncthreads();
  }

  float4 b4 = *(const float4*)(bias + c0);
  float ps[4] = {0.f, 0.f, 0.f, 0.f};
  float pq[4] = {0.f, 0.f, 0.f, 0.f};
#pragma unroll
  for (int i = 0; i < 8; ++i) {
    int row = row_base + r0 + i;
    if (row < N_NODES) {
      float4 y;
      y.x = acc[i][0] + b4.x;
      y.y = acc[i][1] + b4.y;
      y.z = acc[i][2] + b4.z;
      y.w = acc[i][3] + b4.w;
      *(float4*)(Y + (size_t)row * 128 + c0) = y;
      if (scaled_out) {
        float ns = norm_src[row];
        union { __half2 h[2]; float2 f; } u;
        u.h[0] = __floats2half2_rn(y.x * ns, y.y * ns);
        u.h[1] = __floats2half2_rn(y.z * ns, y.w * ns);
        *(float2*)(scaled_out + (size_t)row * 128 + c0) = u.f;
      }
      ps[0] += y.x; ps[1] += y.y; ps[2] += y.z; ps[3] += y.w;
      pq[0] += y.x * y.x; pq[1] += y.y * y.y;
      pq[2] += y.z * y.z; pq[3] += y.w * y.w;
    }
  }
  if (stats) {
    float* red = sXt;              // [16][132]
    float* red2 = sXt + 16 * 132;  // [16][132]
#pragma unroll
    for (int j = 0; j < 4; ++j) {
      red[trow * 132 + c0 + j] = ps[j];
      red2[trow * 132 + c0 + j] = pq[j];
    }
    __syncthreads();
    if (tid < 128) {
      float s = 0.f, q = 0.f;
#pragma unroll
      for (int t = 0; t < 16; ++t) {
        s += red[t * 132 + tid];
        q += red2[t * 132 + tid];
      }
      atomicAdd(&stats[tid], s);
      atomicAdd(&stats[128 + tid], q);
    }
  }
}

// ---------------- BN finalize ----------------
__global__ __launch_bounds__(128) void bn_fin_k(const float* __restrict__ stats,
                                                const float* __restrict__ gamma,
                                                const float* __restrict__ beta,
                                                float* __restrict__ sc_sh) {
  int c = threadIdx.x;
  const float invn = 1.0f / (float)N_NODES;
  float mean = stats[c] * invn;
  float var = stats[128 + c] * invn - mean * mean;
  var = fmaxf(var, 0.f);
  float sc = gamma[c] * rsqrtf(var + BN_EPS);
  sc_sh[c] = sc;
  sc_sh[128 + c] = beta[c] - mean * sc;
}

// ---------------- BN apply + ReLU + residual (+ fp16 scale for gather) -----
__global__ __launch_bounds__(256) void bnrelu_k(
    const float4* __restrict__ hl, float4* __restrict__ A,
    __half* __restrict__ S, const float* __restrict__ sc_sh,
    const float* __restrict__ norm_src, int write_scaled) {
  int idx = blockIdx.x * 256 + threadIdx.x;  // < N_NODES*32
  int node = idx >> 5;
  int c4 = idx & 31;
  const float4* sv = (const float4*)sc_sh;
  float4 s = sv[c4], b = sv[32 + c4];
  float4 hv = hl[idx], av = A[idx];
  float4 v;
  v.x = fmaxf(hv.x * s.x + b.x, 0.f) + av.x;
  v.y = fmaxf(hv.y * s.y + b.y, 0.f) + av.y;
  v.z = fmaxf(hv.z * s.z + b.z, 0.f) + av.z;
  v.w = fmaxf(hv.w * s.w + b.w, 0.f) + av.w;
  A[idx] = v;
  if (write_scaled) {
    float n = norm_src[node];
    union { __half2 h[2]; float2 f; } u;
    u.h[0] = __floats2half2_rn(v.x * n, v.y * n);
    u.h[1] = __floats2half2_rn(v.z * n, v.w * n);
    *(float2*)(S + (size_t)node * 128 + c4 * 4) = u.f;
  }
}

// ---------------- pull aggregation (fp16 operand) ----------------
// agg[i] = norm_dst[i] * sum_{e: dst=i} Hs[src_e], Hs rows are 128 halves
// (256 B). 16 lanes per node, each lane owns 8 consecutive cols (one 16B
// float4 = 8 halves). fp32 accumulation.
__device__ inline void acc8(float (&a)[8], float4 v) {
  const __half2* hp = (const __half2*)&v;
  float2 f;
  f = __half22float2(hp[0]); a[0] += f.x; a[1] += f.y;
  f = __half22float2(hp[1]); a[2] += f.x; a[3] += f.y;
  f = __half22float2(hp[2]); a[4] += f.x; a[5] += f.y;
  f = __half22float2(hp[3]); a[6] += f.x; a[7] += f.y;
}

__global__ __launch_bounds__(256) void gather_k(
    const float4* __restrict__ Hs, const int* __restrict__ row_start,
    const int* __restrict__ csr_src, const float* __restrict__ norm_dst,
    float* __restrict__ out) {
  int node = (blockIdx.x * 256 + threadIdx.x) >> 4;
  int lane = threadIdx.x & 15;
  if (node >= N_NODES) return;
  int s0 = row_start[node], s1 = row_start[node + 1];
  float a[8] = {0.f, 0.f, 0.f, 0.f, 0.f, 0.f, 0.f, 0.f};
  for (int e = s0; e < s1; e += 16) {
    int cnt = s1 - e;
    if (cnt > 16) cnt = 16;
    int idx = (lane < cnt) ? csr_src[e + lane] : 0;
    int j = 0;
    for (; j + 2 <= cnt; j += 2) {
      int sa = __shfl(idx, j, 16);
      int sb = __shfl(idx, j + 1, 16);
      float4 va = Hs[(size_t)sa * 16 + lane];
      float4 vb = Hs[(size_t)sb * 16 + lane];
      acc8(a, va);
      acc8(a, vb);
    }
    if (j < cnt) {
      int sa = __shfl(idx, j, 16);
      acc8(a, Hs[(size_t)sa * 16 + lane]);
    }
  }
  float nd = norm_dst[node];
  float4* op = (float4*)(out + (size_t)node * 128 + lane * 8);
  op[0] = make_float4(a[0] * nd, a[1] * nd, a[2] * nd, a[3] * nd);
  op[1] = make_float4(a[4] * nd, a[5] * nd, a[6] * nd, a[7] * nd);
}

// ---------------- readout ----------------
__global__ __launch_bounds__(256) void gbounds_k(const int* __restrict__ gid,
                                                 int* __restrict__ gstart) {
  int g = threadIdx.x;  // 0..128
  if (g > N_GRAPHS) return;
  int lo = 0, hi = N_NODES;
  while (lo < hi) {
    int mid = (lo + hi) >> 1;
    if (gid[mid] < g) lo = mid + 1; else hi = mid;
  }
  gstart[g] = lo;
}

__global__ __launch_bounds__(128) void gsum_k(const float* __restrict__ A,
                                              const int* __restrict__ gid,
                                              float* gsum) {
  int c = threadIdx.x;
  int n0 = blockIdx.x * 128;
  int n1 = n0 + 128;
  if (n1 > N_NODES) n1 = N_NODES;
  int cur = gid[n0];
  float local = 0.f;
  for (int n = n0; n < n1; ++n) {
    int g = gid[n];  // sorted: few changes per block
    if (g != cur) {
      atomicAdd(&gsum[cur * 128 + c], local);
      local = 0.f;
      cur = g;
    }
    local += A[(size_t)n * 128 + c];
  }
  atomicAdd(&gsum[cur * 128 + c], local);
}

__global__ __launch_bounds__(128) void gout_k(const float* __restrict__ gsum,
                                              const int* __restrict__ gstart,
                                              float* __restrict__ out) {
  int g = blockIdx.x, c = threadIdx.x;
  float cnt = (float)(gstart[g + 1] - gstart[g]);
  if (cnt < 1.f) cnt = 1.f;
  out[g * 128 + c] = gsum[g * 128 + c] / cnt;
}

// ---------------- launch ----------------
extern "C" void kernel_launch(void* const* d_in, const int* in_sizes, int n_in,
                              void* d_out, int out_size, void* d_ws,
                              size_t ws_size, hipStream_t stream) {
  const float* h = (const float*)d_in[0];
  const int* src = (const int*)d_in[1];
  const int* dst = (const int*)d_in[2];
  const int* gid = (const int*)d_in[3];
  const float* W_embed = (const float*)d_in[4];
  const float* b_embed = (const float*)d_in[5];
  const float* W_layers = (const float*)d_in[6];
  const float* b_layers = (const float*)d_in[7];
  const float* gamma = (const float*)d_in[8];
  const float* beta = (const float*)d_in[9];
  float* out = (float*)d_out;
  (void)in_sizes; (void)n_in; (void)out_size; (void)ws_size;

  char* ws = (char*)d_ws;
  size_t o = 0;
  auto alloc = [&](size_t bytes) -> char* {
    char* p = ws + o;
    o = (o + bytes + 255) & ~(size_t)255;
    return p;
  };
  float* norm_src = (float*)alloc(N_NODES * 4);
  float* norm_dst = (float*)alloc(N_NODES * 4);
  int* deg_out = (int*)alloc(N_NODES * 4);  // reused as fill cursor
  int* deg_in = (int*)alloc(N_NODES * 4);   // adjacent to deg_out (one memset)
  int* row_start = (int*)alloc((N_NODES + 1) * 4);
  int* bsums = (int*)alloc(SCAN_NB * 4);
  int* csr_src = (int*)alloc((size_t)N_EDGES * 4);
  float* stats4 = (float*)alloc(N_LAYERS * 256 * 4);  // per-layer sum|sumsq
  float* gsum = (float*)alloc(N_GRAPHS * 128 * 4);    // adjacent to stats4
  int* gstart = (int*)alloc((N_GRAPHS + 1) * 4);
  float* sc_sh = (float*)alloc(256 * 4);
  float* A = (float*)alloc((size_t)N_NODES * 128 * 4);   // residual h
  __half* P0 = (__half*)alloc((size_t)N_NODES * 128 * 2);  // fp16 h*norm_src
  float* P1 = (float*)alloc((size_t)N_NODES * 128 * 4);  // agg / hl (in-place)

  // zero accumulators (deg_out+deg_in contiguous; stats4+gsum contiguous)
  hipMemsetAsync(deg_out, 0, 2 * 400128, stream);
  hipMemsetAsync(stats4, 0, 4096 + 65536, stream);

  degree_k<<<(N_EDGES + 255) / 256, 256, 0, stream>>>(src, dst, deg_out, deg_in);
  norm_k<<<(N_NODES + 255) / 256, 256, 0, stream>>>(deg_out, deg_in, norm_src,
                                                    norm_dst);
  scan1_k<<<SCAN_NB, 256, 0, stream>>>(deg_in, bsums);
  scan2_k<<<1, 128, 0, stream>>>(bsums, row_start);
  scan3_k<<<SCAN_NB, 256, 0, stream>>>(deg_in, bsums, row_start);
  hipMemcpyAsync(deg_out, row_start, N_NODES * 4, hipMemcpyDeviceToDevice,
                 stream);  // cursor = row_start copy
  fill_k<<<(N_EDGES + 255) / 256, 256, 0, stream>>>(src, dst, deg_out, csr_src);

  // embed: A = h @ W_embed + b ; P0 = fp16(A * norm_src)
  gemm128<<<(N_NODES + 127) / 128, 512, 0, stream>>>(h, W_embed, b_embed, A, P0,
                                                     norm_src, nullptr);

  for (int l = 0; l < N_LAYERS; ++l) {
    gather_k<<<(N_NODES * 16 + 255) / 256, 256, 0, stream>>>(
        (const float4*)P0, row_start, csr_src, norm_dst, P1);
    gemm128<<<(N_NODES + 127) / 128, 512, 0, stream>>>(
        P1, W_layers + (size_t)l * DIM * DIM, b_layers + l * DIM, P1, nullptr,
        nullptr, stats4 + l * 256);
    bn_fin_k<<<1, 128, 0, stream>>>(stats4 + l * 256, gamma + l * DIM,
                                    beta + l * DIM, sc_sh);
    bnrelu_k<<<(N_NODES * 32 + 255) / 256, 256, 0, stream>>>(
        (const float4*)P1, (float4*)A, P0, sc_sh, norm_src,
        (l < N_LAYERS - 1) ? 1 : 0);
  }

  gbounds_k<<<1, 256, 0, stream>>>(gid, gstart);
  gsum_k<<<(N_NODES + 127) / 128, 128, 0, stream>>>(A, gid, gsum);
  gout_k<<<N_GRAPHS, 128, 0, stream>>>(gsum, gstart, out);
}

// Round 4
// 1004.163 us; speedup vs baseline: 1.6879x; 1.0835x over previous
//
#include <hip/hip_runtime.h>
#include <hip/hip_bf16.h>
#include <hip/hip_fp16.h>

// GCN forward. fp16 storage for gather operand + GEMM inputs; fp32 accum
// everywhere (gather accum, MFMA accum, BN stats, residual, readout).
// R1: gcnt via binary search (was 285us atomic histogram).
// R2: fp16 gather operand, 16 lanes/node gather.
// R3: v_mfma_f32_16x16x32_f16 GEMM (fp32 has no MFMA on CDNA4); W pre-swizzled
//     to B-frag layout; gather writes fp16; h converted to fp16 once.

#define N_NODES 100000
#define N_EDGES 1600000
#define N_GRAPHS 128
#define DIM 128
#define N_LAYERS 4
#define BN_EPS 1e-5f
#define SCAN_NB 98  // ceil(N_NODES / 1024)

typedef __attribute__((ext_vector_type(8))) _Float16 half8;
typedef __attribute__((ext_vector_type(4))) float floatx4;

// ---------------- degree / norms ----------------
__global__ __launch_bounds__(256) void degree_k(const int* __restrict__ src,
                                                const int* __restrict__ dst,
                                                int* deg_out, int* deg_in) {
  int e = blockIdx.x * 256 + threadIdx.x;
  if (e < N_EDGES) {
    atomicAdd(&deg_out[src[e]], 1);
    atomicAdd(&deg_in[dst[e]], 1);
  }
}

__global__ __launch_bounds__(256) void norm_k(const int* __restrict__ deg_out,
                                              const int* __restrict__ deg_in,
                                              float* __restrict__ norm_src,
                                              float* __restrict__ norm_dst) {
  int i = blockIdx.x * 256 + threadIdx.x;
  if (i < N_NODES) {
    int dso = deg_out[i] > 1 ? deg_out[i] : 1;
    int dsi = deg_in[i] > 1 ? deg_in[i] : 1;
    norm_src[i] = rsqrtf((float)dso);
    norm_dst[i] = rsqrtf((float)dsi);
  }
}

// ---------------- exclusive scan of deg_in -> row_start ----------------
__global__ __launch_bounds__(256) void scan1_k(const int* __restrict__ deg,
                                               int* __restrict__ bsums) {
  __shared__ int sred[256];
  int t = threadIdx.x;
  int i0 = blockIdx.x * 1024 + t * 4;
  int s = 0;
#pragma unroll
  for (int j = 0; j < 4; ++j) {
    int i = i0 + j;
    s += (i < N_NODES) ? deg[i] : 0;
  }
  sred[t] = s;
  __syncthreads();
  for (int off = 128; off > 0; off >>= 1) {
    if (t < off) sred[t] += sred[t + off];
    __syncthreads();
  }
  if (t == 0) bsums[blockIdx.x] = sred[0];
}

__global__ __launch_bounds__(128) void scan2_k(int* __restrict__ bsums,
                                               int* __restrict__ row_start) {
  __shared__ int sd[128];
  int t = threadIdx.x;
  int v = (t < SCAN_NB) ? bsums[t] : 0;
  sd[t] = v;
  __syncthreads();
  for (int off = 1; off < 128; off <<= 1) {
    int tmp = (t >= off) ? sd[t - off] : 0;
    __syncthreads();
    sd[t] += tmp;
    __syncthreads();
  }
  if (t < SCAN_NB) bsums[t] = sd[t] - v;  // exclusive
  if (t == 0) row_start[N_NODES] = N_EDGES;
}

__global__ __launch_bounds__(256) void scan3_k(const int* __restrict__ deg,
                                               const int* __restrict__ bsums,
                                               int* __restrict__ row_start) {
  __shared__ int sd[256];
  int t = threadIdx.x;
  int i0 = blockIdx.x * 1024 + t * 4;
  int d[4];
  int tot = 0;
#pragma unroll
  for (int j = 0; j < 4; ++j) {
    int i = i0 + j;
    d[j] = (i < N_NODES) ? deg[i] : 0;
    tot += d[j];
  }
  sd[t] = tot;
  __syncthreads();
  for (int off = 1; off < 256; off <<= 1) {
    int tmp = (t >= off) ? sd[t - off] : 0;
    __syncthreads();
    sd[t] += tmp;
    __syncthreads();
  }
  int run = bsums[blockIdx.x] + sd[t] - tot;
#pragma unroll
  for (int j = 0; j < 4; ++j) {
    int i = i0 + j;
    if (i < N_NODES) row_start[i] = run;
    run += d[j];
  }
}

__global__ __launch_bounds__(256) void fill_k(const int* __restrict__ src,
                                              const int* __restrict__ dst,
                                              int* __restrict__ cursor,
                                              int* __restrict__ csr_src) {
  int e = blockIdx.x * 256 + threadIdx.x;
  if (e < N_EDGES) {
    int d = dst[e];
    int pos = atomicAdd(&cursor[d], 1);
    csr_src[pos] = src[e];
  }
}

// ---------------- fp32 -> fp16 convert (h) ----------------
__global__ __launch_bounds__(256) void h2h_k(const float* __restrict__ in,
                                             __half* __restrict__ out) {
  int i = blockIdx.x * 256 + threadIdx.x;  // one per 8 elems
  if (i < N_NODES * 16) {
    float4 a = ((const float4*)in)[(size_t)i * 2];
    float4 b = ((const float4*)in)[(size_t)i * 2 + 1];
    union { __half2 h[4]; float4 f; } u;
    u.h[0] = __floats2half2_rn(a.x, a.y);
    u.h[1] = __floats2half2_rn(a.z, a.w);
    u.h[2] = __floats2half2_rn(b.x, b.y);
    u.h[3] = __floats2half2_rn(b.z, b.w);
    ((float4*)out)[i] = u.f;
  }
}

// ---------------- W pre-swizzle to B-fragment layout ----------------
// Bsw[mat][ct][ks][lane][j] = fp16( W[mat][ k=ks*32+(lane>>4)*8+j ][ n=ct*16+(lane&15) ] )
// 16384 halves (32 KB) per matrix. grid = nmat*8 blocks of 256.
__global__ __launch_bounds__(256) void wswz_k(const float* __restrict__ W,
                                              __half* __restrict__ Bsw) {
  int w = blockIdx.x >> 3, ct = blockIdx.x & 7;
  int ks = threadIdx.x >> 6, lane = threadIdx.x & 63;
  int n = ct * 16 + (lane & 15);
  int k0 = ks * 32 + (lane >> 4) * 8;
  const float* Wm = W + (size_t)w * 16384;
  __half* o = Bsw + ((((size_t)w * 8 + ct) * 4 + ks) * 64 + lane) * 8;
#pragma unroll
  for (int j = 0; j < 8; ++j) o[j] = __float2half(Wm[(k0 + j) * 128 + n]);
}

// ---------------- MFMA GEMM: Y[N,128] = X16[N,128] @ W + b ----------------
// 256 thr = 4 waves; block does 128 rows. Wave w: rows [w*32, w*32+32) as two
// 16-row tiles x eight 16-col tiles, K=128 in four 32-chunks.
// A staged in LDS (row stride 136 halves -> worst 2-way bank alias = free).
// B-frags from pre-swizzled global (L2-hot). fp32 accum.
// Epilogue: +bias, fp32 store, optional fp16 scaled copy, optional BN stats.
__global__ __launch_bounds__(256) void mfma_gemm(
    const __half* __restrict__ X16, const __half* __restrict__ Bsw,
    const float* __restrict__ bias, float* __restrict__ Yf,
    __half* __restrict__ S16, const float* __restrict__ norm_src,
    float* stats) {
  __shared__ __half sA[128 * 136];  // 34.8 KB
  const int tid = threadIdx.x;
  const int w = tid >> 6;
  const int lane = tid & 63;
  const int quad = lane >> 4;
  const int lrow = lane & 15;
  const int row_base = blockIdx.x * 128;

  // stage A tile [128][128] fp16, coalesced float4 reads
#pragma unroll
  for (int i = 0; i < 8; ++i) {
    int g = i * 256 + tid;  // float4 index in tile (16 per row)
    int r = g >> 4, p = g & 15;
    int row = row_base + r;
    float4 v = make_float4(0.f, 0.f, 0.f, 0.f);
    if (row < N_NODES) v = ((const float4*)X16)[(size_t)row * 16 + p];
    *(float4*)(&sA[r * 136 + p * 8]) = v;
  }
  __syncthreads();

  floatx4 acc[2][8];
#pragma unroll
  for (int tr = 0; tr < 2; ++tr)
#pragma unroll
    for (int ct = 0; ct < 8; ++ct) acc[tr][ct] = (floatx4)(0.f);

#pragma unroll
  for (int ks = 0; ks < 4; ++ks) {
    half8 afrag[2];
#pragma unroll
    for (int tr = 0; tr < 2; ++tr) {
      int m = w * 32 + tr * 16 + lrow;
      afrag[tr] = *(const half8*)(&sA[m * 136 + ks * 32 + quad * 8]);
    }
#pragma unroll
    for (int ct = 0; ct < 8; ++ct) {
      half8 bfrag = *(const half8*)(&Bsw[(((size_t)ct * 4 + ks) * 64 + lane) * 8]);
      acc[0][ct] = __builtin_amdgcn_mfma_f32_16x16x32_f16(afrag[0], bfrag,
                                                          acc[0][ct], 0, 0, 0);
      acc[1][ct] = __builtin_amdgcn_mfma_f32_16x16x32_f16(afrag[1], bfrag,
                                                          acc[1][ct], 0, 0, 0);
    }
  }

  // epilogue. C layout: row = tr*16 + quad*4 + reg, col = ct*16 + lrow.
  int rowv[2][4];
  float nsv[2][4];
#pragma unroll
  for (int tr = 0; tr < 2; ++tr)
#pragma unroll
    for (int reg = 0; reg < 4; ++reg) {
      int row = row_base + w * 32 + tr * 16 + quad * 4 + reg;
      rowv[tr][reg] = row;
      nsv[tr][reg] = (S16 && row < N_NODES) ? norm_src[row] : 0.f;
    }

  float psum[8], pqsum[8];
#pragma unroll
  for (int ct = 0; ct < 8; ++ct) {
    int col = ct * 16 + lrow;
    float b = bias[col];
    psum[ct] = 0.f;
    pqsum[ct] = 0.f;
#pragma unroll
    for (int tr = 0; tr < 2; ++tr)
#pragma unroll
      for (int reg = 0; reg < 4; ++reg) {
        int row = rowv[tr][reg];
        if (row < N_NODES) {
          float y = acc[tr][ct][reg] + b;
          Yf[(size_t)row * 128 + col] = y;
          if (S16)
            S16[(size_t)row * 128 + col] = __float2half(y * nsv[tr][reg]);
          psum[ct] += y;
          pqsum[ct] += y * y;
        }
      }
  }

  if (stats) {
    // reduce across quads (same col lives in 4 quads of the wave)
#pragma unroll
    for (int ct = 0; ct < 8; ++ct) {
      psum[ct] += __shfl_xor(psum[ct], 16, 64);
      psum[ct] += __shfl_xor(psum[ct], 32, 64);
      pqsum[ct] += __shfl_xor(pqsum[ct], 16, 64);
      pqsum[ct] += __shfl_xor(pqsum[ct], 32, 64);
    }
    __syncthreads();  // sA no longer needed
    float* sred = (float*)sA;  // [4 waves][128] sum, then [4][128] sumsq
    if (quad == 0) {
#pragma unroll
      for (int ct = 0; ct < 8; ++ct) {
        sred[w * 128 + ct * 16 + lrow] = psum[ct];
        sred[512 + w * 128 + ct * 16 + lrow] = pqsum[ct];
      }
    }
    __syncthreads();
    if (tid < 128) {
      float s = sred[tid] + sred[128 + tid] + sred[256 + tid] + sred[384 + tid];
      float q = sred[512 + tid] + sred[640 + tid] + sred[768 + tid] +
                sred[896 + tid];
      atomicAdd(&stats[tid], s);
      atomicAdd(&stats[128 + tid], q);
    }
  }
}

// ---------------- BN finalize ----------------
__global__ __launch_bounds__(128) void bn_fin_k(const float* __restrict__ stats,
                                                const float* __restrict__ gamma,
                                                const float* __restrict__ beta,
                                                float* __restrict__ sc_sh) {
  int c = threadIdx.x;
  const float invn = 1.0f / (float)N_NODES;
  float mean = stats[c] * invn;
  float var = stats[128 + c] * invn - mean * mean;
  var = fmaxf(var, 0.f);
  float sc = gamma[c] * rsqrtf(var + BN_EPS);
  sc_sh[c] = sc;
  sc_sh[128 + c] = beta[c] - mean * sc;
}

// ---------------- BN apply + ReLU + residual (+ fp16 scale for gather) -----
__global__ __launch_bounds__(256) void bnrelu_k(
    const float4* __restrict__ hl, float4* __restrict__ A,
    __half* __restrict__ S, const float* __restrict__ sc_sh,
    const float* __restrict__ norm_src, int write_scaled) {
  int idx = blockIdx.x * 256 + threadIdx.x;  // < N_NODES*32
  int node = idx >> 5;
  int c4 = idx & 31;
  const float4* sv = (const float4*)sc_sh;
  float4 s = sv[c4], b = sv[32 + c4];
  float4 hv = hl[idx], av = A[idx];
  float4 v;
  v.x = fmaxf(hv.x * s.x + b.x, 0.f) + av.x;
  v.y = fmaxf(hv.y * s.y + b.y, 0.f) + av.y;
  v.z = fmaxf(hv.z * s.z + b.z, 0.f) + av.z;
  v.w = fmaxf(hv.w * s.w + b.w, 0.f) + av.w;
  A[idx] = v;
  if (write_scaled) {
    float n = norm_src[node];
    union { __half2 h[2]; float2 f; } u;
    u.h[0] = __floats2half2_rn(v.x * n, v.y * n);
    u.h[1] = __floats2half2_rn(v.z * n, v.w * n);
    *(float2*)(S + (size_t)node * 128 + c4 * 4) = u.f;
  }
}

// ---------------- pull aggregation (fp16 operand, fp16 output) ----------------
__device__ inline void acc8(float (&a)[8], float4 v) {
  const __half2* hp = (const __half2*)&v;
  float2 f;
  f = __half22float2(hp[0]); a[0] += f.x; a[1] += f.y;
  f = __half22float2(hp[1]); a[2] += f.x; a[3] += f.y;
  f = __half22float2(hp[2]); a[4] += f.x; a[5] += f.y;
  f = __half22float2(hp[3]); a[6] += f.x; a[7] += f.y;
}

__global__ __launch_bounds__(256) void gather_k(
    const float4* __restrict__ Hs, const int* __restrict__ row_start,
    const int* __restrict__ csr_src, const float* __restrict__ norm_dst,
    __half* __restrict__ out) {
  int node = (blockIdx.x * 256 + threadIdx.x) >> 4;
  int lane = threadIdx.x & 15;
  if (node >= N_NODES) return;
  int s0 = row_start[node], s1 = row_start[node + 1];
  float a[8] = {0.f, 0.f, 0.f, 0.f, 0.f, 0.f, 0.f, 0.f};
  for (int e = s0; e < s1; e += 16) {
    int cnt = s1 - e;
    if (cnt > 16) cnt = 16;
    int idx = (lane < cnt) ? csr_src[e + lane] : 0;
    int j = 0;
    for (; j + 2 <= cnt; j += 2) {
      int sa = __shfl(idx, j, 16);
      int sb = __shfl(idx, j + 1, 16);
      float4 va = Hs[(size_t)sa * 16 + lane];
      float4 vb = Hs[(size_t)sb * 16 + lane];
      acc8(a, va);
      acc8(a, vb);
    }
    if (j < cnt) {
      int sa = __shfl(idx, j, 16);
      acc8(a, Hs[(size_t)sa * 16 + lane]);
    }
  }
  float nd = norm_dst[node];
  union { __half2 h[4]; float4 f; } u;
  u.h[0] = __floats2half2_rn(a[0] * nd, a[1] * nd);
  u.h[1] = __floats2half2_rn(a[2] * nd, a[3] * nd);
  u.h[2] = __floats2half2_rn(a[4] * nd, a[5] * nd);
  u.h[3] = __floats2half2_rn(a[6] * nd, a[7] * nd);
  ((float4*)(out + (size_t)node * 128))[lane] = u.f;
}

// ---------------- readout ----------------
__global__ __launch_bounds__(256) void gbounds_k(const int* __restrict__ gid,
                                                 int* __restrict__ gstart) {
  int g = threadIdx.x;  // 0..128
  if (g > N_GRAPHS) return;
  int lo = 0, hi = N_NODES;
  while (lo < hi) {
    int mid = (lo + hi) >> 1;
    if (gid[mid] < g) lo = mid + 1; else hi = mid;
  }
  gstart[g] = lo;
}

__global__ __launch_bounds__(128) void gsum_k(const float* __restrict__ A,
                                              const int* __restrict__ gid,
                                              float* gsum) {
  int c = threadIdx.x;
  int n0 = blockIdx.x * 128;
  int n1 = n0 + 128;
  if (n1 > N_NODES) n1 = N_NODES;
  int cur = gid[n0];
  float local = 0.f;
  for (int n = n0; n < n1; ++n) {
    int g = gid[n];  // sorted: few changes per block
    if (g != cur) {
      atomicAdd(&gsum[cur * 128 + c], local);
      local = 0.f;
      cur = g;
    }
    local += A[(size_t)n * 128 + c];
  }
  atomicAdd(&gsum[cur * 128 + c], local);
}

__global__ __launch_bounds__(128) void gout_k(const float* __restrict__ gsum,
                                              const int* __restrict__ gstart,
                                              float* __restrict__ out) {
  int g = blockIdx.x, c = threadIdx.x;
  float cnt = (float)(gstart[g + 1] - gstart[g]);
  if (cnt < 1.f) cnt = 1.f;
  out[g * 128 + c] = gsum[g * 128 + c] / cnt;
}

// ---------------- launch ----------------
extern "C" void kernel_launch(void* const* d_in, const int* in_sizes, int n_in,
                              void* d_out, int out_size, void* d_ws,
                              size_t ws_size, hipStream_t stream) {
  const float* h = (const float*)d_in[0];
  const int* src = (const int*)d_in[1];
  const int* dst = (const int*)d_in[2];
  const int* gid = (const int*)d_in[3];
  const float* W_embed = (const float*)d_in[4];
  const float* b_embed = (const float*)d_in[5];
  const float* W_layers = (const float*)d_in[6];
  const float* b_layers = (const float*)d_in[7];
  const float* gamma = (const float*)d_in[8];
  const float* beta = (const float*)d_in[9];
  float* out = (float*)d_out;
  (void)in_sizes; (void)n_in; (void)out_size; (void)ws_size;

  char* ws = (char*)d_ws;
  size_t o = 0;
  auto alloc = [&](size_t bytes) -> char* {
    char* p = ws + o;
    o = (o + bytes + 255) & ~(size_t)255;
    return p;
  };
  float* norm_src = (float*)alloc(N_NODES * 4);
  float* norm_dst = (float*)alloc(N_NODES * 4);
  int* deg_out = (int*)alloc(N_NODES * 4);  // reused as fill cursor
  int* deg_in = (int*)alloc(N_NODES * 4);   // adjacent to deg_out (one memset)
  int* row_start = (int*)alloc((N_NODES + 1) * 4);
  int* bsums = (int*)alloc(SCAN_NB * 4);
  int* csr_src = (int*)alloc((size_t)N_EDGES * 4);
  float* stats4 = (float*)alloc(N_LAYERS * 256 * 4);  // per-layer sum|sumsq
  float* gsum = (float*)alloc(N_GRAPHS * 128 * 4);    // adjacent to stats4
  int* gstart = (int*)alloc((N_GRAPHS + 1) * 4);
  float* sc_sh = (float*)alloc(256 * 4);
  __half* Bsw = (__half*)alloc(5 * 16384 * 2);  // swizzled W: embed + 4 layers
  float* A = (float*)alloc((size_t)N_NODES * 128 * 4);     // residual h (fp32)
  float* P1f = (float*)alloc((size_t)N_NODES * 128 * 4);   // hl (fp32)
  __half* P0h = (__half*)alloc((size_t)N_NODES * 128 * 2); // h*norm_src (fp16)
  __half* P1h = (__half*)alloc((size_t)N_NODES * 128 * 2); // h16 / agg (fp16)

  // zero accumulators (deg_out+deg_in contiguous; stats4+gsum contiguous)
  hipMemsetAsync(deg_out, 0, 2 * 400128, stream);
  hipMemsetAsync(stats4, 0, 4096 + 65536, stream);

  degree_k<<<(N_EDGES + 255) / 256, 256, 0, stream>>>(src, dst, deg_out, deg_in);
  norm_k<<<(N_NODES + 255) / 256, 256, 0, stream>>>(deg_out, deg_in, norm_src,
                                                    norm_dst);
  scan1_k<<<SCAN_NB, 256, 0, stream>>>(deg_in, bsums);
  scan2_k<<<1, 128, 0, stream>>>(bsums, row_start);
  scan3_k<<<SCAN_NB, 256, 0, stream>>>(deg_in, bsums, row_start);
  hipMemcpyAsync(deg_out, row_start, N_NODES * 4, hipMemcpyDeviceToDevice,
                 stream);  // cursor = row_start copy
  fill_k<<<(N_EDGES + 255) / 256, 256, 0, stream>>>(src, dst, deg_out, csr_src);

  // W swizzle + h fp16 convert
  wswz_k<<<8, 256, 0, stream>>>(W_embed, Bsw);
  wswz_k<<<32, 256, 0, stream>>>(W_layers, Bsw + 16384);
  h2h_k<<<(N_NODES * 16 + 255) / 256, 256, 0, stream>>>(h, P1h);

  // embed: A = h16 @ W_embed + b ; P0h = fp16(A * norm_src)
  mfma_gemm<<<(N_NODES + 127) / 128, 256, 0, stream>>>(
      P1h, Bsw, b_embed, A, P0h, norm_src, nullptr);

  for (int l = 0; l < N_LAYERS; ++l) {
    gather_k<<<(N_NODES * 16 + 255) / 256, 256, 0, stream>>>(
        (const float4*)P0h, row_start, csr_src, norm_dst, P1h);
    mfma_gemm<<<(N_NODES + 127) / 128, 256, 0, stream>>>(
        P1h, Bsw + (size_t)(1 + l) * 16384, b_layers + l * DIM, P1f, nullptr,
        nullptr, stats4 + l * 256);
    bn_fin_k<<<1, 128, 0, stream>>>(stats4 + l * 256, gamma + l * DIM,
                                    beta + l * DIM, sc_sh);
    bnrelu_k<<<(N_NODES * 32 + 255) / 256, 256, 0, stream>>>(
        (const float4*)P1f, (float4*)A, P0h, sc_sh, norm_src,
        (l < N_LAYERS - 1) ? 1 : 0);
  }

  gbounds_k<<<1, 256, 0, stream>>>(gid, gstart);
  gsum_k<<<(N_NODES + 127) / 128, 128, 0, stream>>>(A, gid, gsum);
  gout_k<<<N_GRAPHS, 128, 0, stream>>>(gsum, gstart, out);
}

// Round 5
// 929.291 us; speedup vs baseline: 1.8239x; 1.0806x over previous
//
#include <hip/hip_runtime.h>
#include <hip/hip_bf16.h>
#include <hip/hip_fp16.h>

// GCN forward. fp16 storage for gather operand + GEMM inputs; fp32 accum
// everywhere (gather accum, MFMA accum, BN stats, residual, readout).
// R1: gcnt via binary search (was 285us atomic histogram).
// R2: fp16 gather operand, 16 lanes/node gather.
// R3: v_mfma_f32_16x16x32_f16 GEMM; W pre-swizzled to B-frag layout.
// R4: CSR-build rework — deg_out via range-partitioned LDS histogram (kills
//     1.6M scattered atomics); dst atomic returns per-edge rank so fill_k
//     needs no cursor atomic (halves its scattered-transaction count).

#define N_NODES 100000
#define N_EDGES 1600000
#define N_GRAPHS 128
#define DIM 128
#define N_LAYERS 4
#define BN_EPS 1e-5f
#define SCAN_NB 98  // ceil(N_NODES / 1024)

typedef __attribute__((ext_vector_type(8))) _Float16 half8;
typedef __attribute__((ext_vector_type(4))) float floatx4;

// ---------------- deg_out: range-partitioned LDS histogram ----------------
// 4 ranges x 32768 nodes (packed 2x16-bit per u32 word, 64KB LDS);
// 64 chunks of 25000 edges; grid = 4*64 = 256 blocks.
// Per-block count <= 25000 < 2^16 so packed halves cannot overflow/carry.
__global__ __launch_bounds__(256) void histsrc_k(const int* __restrict__ src,
                                                 int* __restrict__ deg_out) {
  __shared__ unsigned sbin[16384];
  int range = blockIdx.x >> 6;  // 0..3
  int chunk = blockIdx.x & 63;  // 0..63
  int base = range << 15;       // *32768
  for (int i = threadIdx.x; i < 16384; i += 256) sbin[i] = 0;
  __syncthreads();
  int e0 = chunk * 25000;
  int e1 = e0 + 25000;  // 64*25000 == N_EDGES exactly
  for (int e = e0 + threadIdx.x; e < e1; e += 256) {
    int s = src[e] - base;
    if ((unsigned)s < 32768u)
      atomicAdd(&sbin[s >> 1], (s & 1) ? 0x10000u : 1u);
  }
  __syncthreads();
  for (int i = threadIdx.x; i < 16384; i += 256) {
    unsigned w = sbin[i];
    if (w) {
      unsigned lo = w & 0xffffu, hi = w >> 16;
      int n0 = base + 2 * i;
      if (lo && n0 < N_NODES) atomicAdd(&deg_out[n0], (int)lo);
      if (hi && n0 + 1 < N_NODES) atomicAdd(&deg_out[n0 + 1], (int)hi);
    }
  }
}

// ---------------- deg_in + per-edge rank (atomic return value) ----------------
__global__ __launch_bounds__(256) void rankdeg_k(const int* __restrict__ dst,
                                                 int* deg_in,
                                                 int* __restrict__ rank) {
  int e = blockIdx.x * 256 + threadIdx.x;
  if (e < N_EDGES) rank[e] = atomicAdd(&deg_in[dst[e]], 1);
}

__global__ __launch_bounds__(256) void norm_k(const int* __restrict__ deg_out,
                                              const int* __restrict__ deg_in,
                                              float* __restrict__ norm_src,
                                              float* __restrict__ norm_dst) {
  int i = blockIdx.x * 256 + threadIdx.x;
  if (i < N_NODES) {
    int dso = deg_out[i] > 1 ? deg_out[i] : 1;
    int dsi = deg_in[i] > 1 ? deg_in[i] : 1;
    norm_src[i] = rsqrtf((float)dso);
    norm_dst[i] = rsqrtf((float)dsi);
  }
}

// ---------------- exclusive scan of deg_in -> row_start ----------------
__global__ __launch_bounds__(256) void scan1_k(const int* __restrict__ deg,
                                               int* __restrict__ bsums) {
  __shared__ int sred[256];
  int t = threadIdx.x;
  int i0 = blockIdx.x * 1024 + t * 4;
  int s = 0;
#pragma unroll
  for (int j = 0; j < 4; ++j) {
    int i = i0 + j;
    s += (i < N_NODES) ? deg[i] : 0;
  }
  sred[t] = s;
  __syncthreads();
  for (int off = 128; off > 0; off >>= 1) {
    if (t < off) sred[t] += sred[t + off];
    __syncthreads();
  }
  if (t == 0) bsums[blockIdx.x] = sred[0];
}

__global__ __launch_bounds__(128) void scan2_k(int* __restrict__ bsums,
                                               int* __restrict__ row_start) {
  __shared__ int sd[128];
  int t = threadIdx.x;
  int v = (t < SCAN_NB) ? bsums[t] : 0;
  sd[t] = v;
  __syncthreads();
  for (int off = 1; off < 128; off <<= 1) {
    int tmp = (t >= off) ? sd[t - off] : 0;
    __syncthreads();
    sd[t] += tmp;
    __syncthreads();
  }
  if (t < SCAN_NB) bsums[t] = sd[t] - v;  // exclusive
  if (t == 0) row_start[N_NODES] = N_EDGES;
}

__global__ __launch_bounds__(256) void scan3_k(const int* __restrict__ deg,
                                               const int* __restrict__ bsums,
                                               int* __restrict__ row_start) {
  __shared__ int sd[256];
  int t = threadIdx.x;
  int i0 = blockIdx.x * 1024 + t * 4;
  int d[4];
  int tot = 0;
#pragma unroll
  for (int j = 0; j < 4; ++j) {
    int i = i0 + j;
    d[j] = (i < N_NODES) ? deg[i] : 0;
    tot += d[j];
  }
  sd[t] = tot;
  __syncthreads();
  for (int off = 1; off < 256; off <<= 1) {
    int tmp = (t >= off) ? sd[t - off] : 0;
    __syncthreads();
    sd[t] += tmp;
    __syncthreads();
  }
  int run = bsums[blockIdx.x] + sd[t] - tot;
#pragma unroll
  for (int j = 0; j < 4; ++j) {
    int i = i0 + j;
    if (i < N_NODES) row_start[i] = run;
    run += d[j];
  }
}

// ---------------- CSR fill, atomic-free (slot = row_start + rank) ----------
__global__ __launch_bounds__(256) void fill2_k(const int* __restrict__ src,
                                               const int* __restrict__ dst,
                                               const int* __restrict__ rank,
                                               const int* __restrict__ row_start,
                                               int* __restrict__ csr_src) {
  int e = blockIdx.x * 256 + threadIdx.x;
  if (e < N_EDGES) csr_src[row_start[dst[e]] + rank[e]] = src[e];
}

// ---------------- fp32 -> fp16 convert (h) ----------------
__global__ __launch_bounds__(256) void h2h_k(const float* __restrict__ in,
                                             __half* __restrict__ out) {
  int i = blockIdx.x * 256 + threadIdx.x;  // one per 8 elems
  if (i < N_NODES * 16) {
    float4 a = ((const float4*)in)[(size_t)i * 2];
    float4 b = ((const float4*)in)[(size_t)i * 2 + 1];
    union { __half2 h[4]; float4 f; } u;
    u.h[0] = __floats2half2_rn(a.x, a.y);
    u.h[1] = __floats2half2_rn(a.z, a.w);
    u.h[2] = __floats2half2_rn(b.x, b.y);
    u.h[3] = __floats2half2_rn(b.z, b.w);
    ((float4*)out)[i] = u.f;
  }
}

// ---------------- W pre-swizzle to B-fragment layout ----------------
// Bsw[mat][ct][ks][lane][j] = fp16( W[mat][ k=ks*32+(lane>>4)*8+j ][ n=ct*16+(lane&15) ] )
__global__ __launch_bounds__(256) void wswz_k(const float* __restrict__ W,
                                              __half* __restrict__ Bsw) {
  int w = blockIdx.x >> 3, ct = blockIdx.x & 7;
  int ks = threadIdx.x >> 6, lane = threadIdx.x & 63;
  int n = ct * 16 + (lane & 15);
  int k0 = ks * 32 + (lane >> 4) * 8;
  const float* Wm = W + (size_t)w * 16384;
  __half* o = Bsw + ((((size_t)w * 8 + ct) * 4 + ks) * 64 + lane) * 8;
#pragma unroll
  for (int j = 0; j < 8; ++j) o[j] = __float2half(Wm[(k0 + j) * 128 + n]);
}

// ---------------- MFMA GEMM: Y[N,128] = X16[N,128] @ W + b ----------------
__global__ __launch_bounds__(256) void mfma_gemm(
    const __half* __restrict__ X16, const __half* __restrict__ Bsw,
    const float* __restrict__ bias, float* __restrict__ Yf,
    __half* __restrict__ S16, const float* __restrict__ norm_src,
    float* stats) {
  __shared__ __half sA[128 * 136];  // 34.8 KB
  const int tid = threadIdx.x;
  const int w = tid >> 6;
  const int lane = tid & 63;
  const int quad = lane >> 4;
  const int lrow = lane & 15;
  const int row_base = blockIdx.x * 128;

  // stage A tile [128][128] fp16, coalesced float4 reads
#pragma unroll
  for (int i = 0; i < 8; ++i) {
    int g = i * 256 + tid;  // float4 index in tile (16 per row)
    int r = g >> 4, p = g & 15;
    int row = row_base + r;
    float4 v = make_float4(0.f, 0.f, 0.f, 0.f);
    if (row < N_NODES) v = ((const float4*)X16)[(size_t)row * 16 + p];
    *(float4*)(&sA[r * 136 + p * 8]) = v;
  }
  __syncthreads();

  floatx4 acc[2][8];
#pragma unroll
  for (int tr = 0; tr < 2; ++tr)
#pragma unroll
    for (int ct = 0; ct < 8; ++ct) acc[tr][ct] = (floatx4)(0.f);

#pragma unroll
  for (int ks = 0; ks < 4; ++ks) {
    half8 afrag[2];
#pragma unroll
    for (int tr = 0; tr < 2; ++tr) {
      int m = w * 32 + tr * 16 + lrow;
      afrag[tr] = *(const half8*)(&sA[m * 136 + ks * 32 + quad * 8]);
    }
#pragma unroll
    for (int ct = 0; ct < 8; ++ct) {
      half8 bfrag = *(const half8*)(&Bsw[(((size_t)ct * 4 + ks) * 64 + lane) * 8]);
      acc[0][ct] = __builtin_amdgcn_mfma_f32_16x16x32_f16(afrag[0], bfrag,
                                                          acc[0][ct], 0, 0, 0);
      acc[1][ct] = __builtin_amdgcn_mfma_f32_16x16x32_f16(afrag[1], bfrag,
                                                          acc[1][ct], 0, 0, 0);
    }
  }

  // epilogue. C layout: row = tr*16 + quad*4 + reg, col = ct*16 + lrow.
  int rowv[2][4];
  float nsv[2][4];
#pragma unroll
  for (int tr = 0; tr < 2; ++tr)
#pragma unroll
    for (int reg = 0; reg < 4; ++reg) {
      int row = row_base + w * 32 + tr * 16 + quad * 4 + reg;
      rowv[tr][reg] = row;
      nsv[tr][reg] = (S16 && row < N_NODES) ? norm_src[row] : 0.f;
    }

  float psum[8], pqsum[8];
#pragma unroll
  for (int ct = 0; ct < 8; ++ct) {
    int col = ct * 16 + lrow;
    float b = bias[col];
    psum[ct] = 0.f;
    pqsum[ct] = 0.f;
#pragma unroll
    for (int tr = 0; tr < 2; ++tr)
#pragma unroll
      for (int reg = 0; reg < 4; ++reg) {
        int row = rowv[tr][reg];
        if (row < N_NODES) {
          float y = acc[tr][ct][reg] + b;
          Yf[(size_t)row * 128 + col] = y;
          if (S16)
            S16[(size_t)row * 128 + col] = __float2half(y * nsv[tr][reg]);
          psum[ct] += y;
          pqsum[ct] += y * y;
        }
      }
  }

  if (stats) {
#pragma unroll
    for (int ct = 0; ct < 8; ++ct) {
      psum[ct] += __shfl_xor(psum[ct], 16, 64);
      psum[ct] += __shfl_xor(psum[ct], 32, 64);
      pqsum[ct] += __shfl_xor(pqsum[ct], 16, 64);
      pqsum[ct] += __shfl_xor(pqsum[ct], 32, 64);
    }
    __syncthreads();  // sA no longer needed
    float* sred = (float*)sA;  // [4 waves][128] sum, then [4][128] sumsq
    if (quad == 0) {
#pragma unroll
      for (int ct = 0; ct < 8; ++ct) {
        sred[w * 128 + ct * 16 + lrow] = psum[ct];
        sred[512 + w * 128 + ct * 16 + lrow] = pqsum[ct];
      }
    }
    __syncthreads();
    if (tid < 128) {
      float s = sred[tid] + sred[128 + tid] + sred[256 + tid] + sred[384 + tid];
      float q = sred[512 + tid] + sred[640 + tid] + sred[768 + tid] +
                sred[896 + tid];
      atomicAdd(&stats[tid], s);
      atomicAdd(&stats[128 + tid], q);
    }
  }
}

// ---------------- BN finalize ----------------
__global__ __launch_bounds__(128) void bn_fin_k(const float* __restrict__ stats,
                                                const float* __restrict__ gamma,
                                                const float* __restrict__ beta,
                                                float* __restrict__ sc_sh) {
  int c = threadIdx.x;
  const float invn = 1.0f / (float)N_NODES;
  float mean = stats[c] * invn;
  float var = stats[128 + c] * invn - mean * mean;
  var = fmaxf(var, 0.f);
  float sc = gamma[c] * rsqrtf(var + BN_EPS);
  sc_sh[c] = sc;
  sc_sh[128 + c] = beta[c] - mean * sc;
}

// ---------------- BN apply + ReLU + residual (+ fp16 scale for gather) -----
__global__ __launch_bounds__(256) void bnrelu_k(
    const float4* __restrict__ hl, float4* __restrict__ A,
    __half* __restrict__ S, const float* __restrict__ sc_sh,
    const float* __restrict__ norm_src, int write_scaled) {
  int idx = blockIdx.x * 256 + threadIdx.x;  // < N_NODES*32
  int node = idx >> 5;
  int c4 = idx & 31;
  const float4* sv = (const float4*)sc_sh;
  float4 s = sv[c4], b = sv[32 + c4];
  float4 hv = hl[idx], av = A[idx];
  float4 v;
  v.x = fmaxf(hv.x * s.x + b.x, 0.f) + av.x;
  v.y = fmaxf(hv.y * s.y + b.y, 0.f) + av.y;
  v.z = fmaxf(hv.z * s.z + b.z, 0.f) + av.z;
  v.w = fmaxf(hv.w * s.w + b.w, 0.f) + av.w;
  A[idx] = v;
  if (write_scaled) {
    float n = norm_src[node];
    union { __half2 h[2]; float2 f; } u;
    u.h[0] = __floats2half2_rn(v.x * n, v.y * n);
    u.h[1] = __floats2half2_rn(v.z * n, v.w * n);
    *(float2*)(S + (size_t)node * 128 + c4 * 4) = u.f;
  }
}

// ---------------- pull aggregation (fp16 operand, fp16 output) ----------------
__device__ inline void acc8(float (&a)[8], float4 v) {
  const __half2* hp = (const __half2*)&v;
  float2 f;
  f = __half22float2(hp[0]); a[0] += f.x; a[1] += f.y;
  f = __half22float2(hp[1]); a[2] += f.x; a[3] += f.y;
  f = __half22float2(hp[2]); a[4] += f.x; a[5] += f.y;
  f = __half22float2(hp[3]); a[6] += f.x; a[7] += f.y;
}

__global__ __launch_bounds__(256) void gather_k(
    const float4* __restrict__ Hs, const int* __restrict__ row_start,
    const int* __restrict__ csr_src, const float* __restrict__ norm_dst,
    __half* __restrict__ out) {
  int node = (blockIdx.x * 256 + threadIdx.x) >> 4;
  int lane = threadIdx.x & 15;
  if (node >= N_NODES) return;
  int s0 = row_start[node], s1 = row_start[node + 1];
  float a[8] = {0.f, 0.f, 0.f, 0.f, 0.f, 0.f, 0.f, 0.f};
  for (int e = s0; e < s1; e += 16) {
    int cnt = s1 - e;
    if (cnt > 16) cnt = 16;
    int idx = (lane < cnt) ? csr_src[e + lane] : 0;
    int j = 0;
    for (; j + 2 <= cnt; j += 2) {
      int sa = __shfl(idx, j, 16);
      int sb = __shfl(idx, j + 1, 16);
      float4 va = Hs[(size_t)sa * 16 + lane];
      float4 vb = Hs[(size_t)sb * 16 + lane];
      acc8(a, va);
      acc8(a, vb);
    }
    if (j < cnt) {
      int sa = __shfl(idx, j, 16);
      acc8(a, Hs[(size_t)sa * 16 + lane]);
    }
  }
  float nd = norm_dst[node];
  union { __half2 h[4]; float4 f; } u;
  u.h[0] = __floats2half2_rn(a[0] * nd, a[1] * nd);
  u.h[1] = __floats2half2_rn(a[2] * nd, a[3] * nd);
  u.h[2] = __floats2half2_rn(a[4] * nd, a[5] * nd);
  u.h[3] = __floats2half2_rn(a[6] * nd, a[7] * nd);
  ((float4*)(out + (size_t)node * 128))[lane] = u.f;
}

// ---------------- readout ----------------
__global__ __launch_bounds__(256) void gbounds_k(const int* __restrict__ gid,
                                                 int* __restrict__ gstart) {
  int g = threadIdx.x;  // 0..128
  if (g > N_GRAPHS) return;
  int lo = 0, hi = N_NODES;
  while (lo < hi) {
    int mid = (lo + hi) >> 1;
    if (gid[mid] < g) lo = mid + 1; else hi = mid;
  }
  gstart[g] = lo;
}

__global__ __launch_bounds__(128) void gsum_k(const float* __restrict__ A,
                                              const int* __restrict__ gid,
                                              float* gsum) {
  int c = threadIdx.x;
  int n0 = blockIdx.x * 128;
  int n1 = n0 + 128;
  if (n1 > N_NODES) n1 = N_NODES;
  int cur = gid[n0];
  float local = 0.f;
  for (int n = n0; n < n1; ++n) {
    int g = gid[n];  // sorted: few changes per block
    if (g != cur) {
      atomicAdd(&gsum[cur * 128 + c], local);
      local = 0.f;
      cur = g;
    }
    local += A[(size_t)n * 128 + c];
  }
  atomicAdd(&gsum[cur * 128 + c], local);
}

__global__ __launch_bounds__(128) void gout_k(const float* __restrict__ gsum,
                                              const int* __restrict__ gstart,
                                              float* __restrict__ out) {
  int g = blockIdx.x, c = threadIdx.x;
  float cnt = (float)(gstart[g + 1] - gstart[g]);
  if (cnt < 1.f) cnt = 1.f;
  out[g * 128 + c] = gsum[g * 128 + c] / cnt;
}

// ---------------- launch ----------------
extern "C" void kernel_launch(void* const* d_in, const int* in_sizes, int n_in,
                              void* d_out, int out_size, void* d_ws,
                              size_t ws_size, hipStream_t stream) {
  const float* h = (const float*)d_in[0];
  const int* src = (const int*)d_in[1];
  const int* dst = (const int*)d_in[2];
  const int* gid = (const int*)d_in[3];
  const float* W_embed = (const float*)d_in[4];
  const float* b_embed = (const float*)d_in[5];
  const float* W_layers = (const float*)d_in[6];
  const float* b_layers = (const float*)d_in[7];
  const float* gamma = (const float*)d_in[8];
  const float* beta = (const float*)d_in[9];
  float* out = (float*)d_out;
  (void)in_sizes; (void)n_in; (void)out_size; (void)ws_size;

  char* ws = (char*)d_ws;
  size_t o = 0;
  auto alloc = [&](size_t bytes) -> char* {
    char* p = ws + o;
    o = (o + bytes + 255) & ~(size_t)255;
    return p;
  };
  float* norm_src = (float*)alloc(N_NODES * 4);
  float* norm_dst = (float*)alloc(N_NODES * 4);
  int* deg_out = (int*)alloc(N_NODES * 4);
  int* deg_in = (int*)alloc(N_NODES * 4);  // adjacent to deg_out (one memset)
  int* row_start = (int*)alloc((N_NODES + 1) * 4);
  int* bsums = (int*)alloc(SCAN_NB * 4);
  int* csr_src = (int*)alloc((size_t)N_EDGES * 4);
  int* rank = (int*)alloc((size_t)N_EDGES * 4);
  float* stats4 = (float*)alloc(N_LAYERS * 256 * 4);  // per-layer sum|sumsq
  float* gsum = (float*)alloc(N_GRAPHS * 128 * 4);    // adjacent to stats4
  int* gstart = (int*)alloc((N_GRAPHS + 1) * 4);
  float* sc_sh = (float*)alloc(256 * 4);
  __half* Bsw = (__half*)alloc(5 * 16384 * 2);  // swizzled W: embed + 4 layers
  float* A = (float*)alloc((size_t)N_NODES * 128 * 4);     // residual h (fp32)
  float* P1f = (float*)alloc((size_t)N_NODES * 128 * 4);   // hl (fp32)
  __half* P0h = (__half*)alloc((size_t)N_NODES * 128 * 2); // h*norm_src (fp16)
  __half* P1h = (__half*)alloc((size_t)N_NODES * 128 * 2); // h16 / agg (fp16)

  // zero accumulators (deg_out+deg_in contiguous; stats4+gsum contiguous)
  hipMemsetAsync(deg_out, 0, 2 * 400128, stream);
  hipMemsetAsync(stats4, 0, 4096 + 65536, stream);

  histsrc_k<<<256, 256, 0, stream>>>(src, deg_out);
  rankdeg_k<<<(N_EDGES + 255) / 256, 256, 0, stream>>>(dst, deg_in, rank);
  norm_k<<<(N_NODES + 255) / 256, 256, 0, stream>>>(deg_out, deg_in, norm_src,
                                                    norm_dst);
  scan1_k<<<SCAN_NB, 256, 0, stream>>>(deg_in, bsums);
  scan2_k<<<1, 128, 0, stream>>>(bsums, row_start);
  scan3_k<<<SCAN_NB, 256, 0, stream>>>(deg_in, bsums, row_start);
  fill2_k<<<(N_EDGES + 255) / 256, 256, 0, stream>>>(src, dst, rank, row_start,
                                                     csr_src);

  // W swizzle + h fp16 convert
  wswz_k<<<8, 256, 0, stream>>>(W_embed, Bsw);
  wswz_k<<<32, 256, 0, stream>>>(W_layers, Bsw + 16384);
  h2h_k<<<(N_NODES * 16 + 255) / 256, 256, 0, stream>>>(h, P1h);

  // embed: A = h16 @ W_embed + b ; P0h = fp16(A * norm_src)
  mfma_gemm<<<(N_NODES + 127) / 128, 256, 0, stream>>>(
      P1h, Bsw, b_embed, A, P0h, norm_src, nullptr);

  for (int l = 0; l < N_LAYERS; ++l) {
    gather_k<<<(N_NODES * 16 + 255) / 256, 256, 0, stream>>>(
        (const float4*)P0h, row_start, csr_src, norm_dst, P1h);
    mfma_gemm<<<(N_NODES + 127) / 128, 256, 0, stream>>>(
        P1h, Bsw + (size_t)(1 + l) * 16384, b_layers + l * DIM, P1f, nullptr,
        nullptr, stats4 + l * 256);
    bn_fin_k<<<1, 128, 0, stream>>>(stats4 + l * 256, gamma + l * DIM,
                                    beta + l * DIM, sc_sh);
    bnrelu_k<<<(N_NODES * 32 + 255) / 256, 256, 0, stream>>>(
        (const float4*)P1f, (float4*)A, P0h, sc_sh, norm_src,
        (l < N_LAYERS - 1) ? 1 : 0);
  }

  gbounds_k<<<1, 256, 0, stream>>>(gid, gstart);
  gsum_k<<<(N_NODES + 127) / 128, 128, 0, stream>>>(A, gid, gsum);
  gout_k<<<N_GRAPHS, 128, 0, stream>>>(gsum, gstart, out);
}